// Round 1
// baseline (2527.731 us; speedup 1.0000x reference)
//
#include <hip/hip_runtime.h>
#include <hip/hip_bf16.h>
#include <math.h>

// Problem constants (SchNet reference)
#define NATOMS 16384
#define NMOL   512
#define APM    32
#define HDIM   128
#define FDIM   128
#define GDIM   50
#define TE     64   // edges per tile in edge kernel

__device__ __forceinline__ float ssp(float x) {
    // shifted softplus: log(1+exp(x)) - log(2)
    return fmaxf(x, 0.0f) + log1pf(expf(-fabsf(x))) - 0.69314718055994531f;
}

// h[i][f] = emb[z[i]][f]
__global__ __launch_bounds__(256) void embed_kernel(
    const int* __restrict__ z, const float* __restrict__ emb,
    float* __restrict__ h)
{
    int idx = blockIdx.x * 256 + threadIdx.x;   // over NATOMS*128
    h[idx] = emb[(size_t)z[idx >> 7] * 128 + (idx & 127)];
}

// Y[n][f] = op( sum_k X[n][k] * W[k][f] + b[f] )   (128x128 weight)
// MODE 0: store, MODE 1: ssp+store, MODE 2: add into Y (residual)
template<int MODE>
__global__ __launch_bounds__(256) void gemm128(
    const float* __restrict__ X, const float* __restrict__ W,
    const float* __restrict__ bias, float* __restrict__ Y, int n)
{
    const int tid = threadIdx.x;
    const int f   = tid & 127;
    const int sub = tid >> 7;
    __shared__ float sx[64][128];

    float wc[128];
    #pragma unroll
    for (int k = 0; k < 128; k++) wc[k] = W[k * 128 + f];
    const float bf = bias ? bias[f] : 0.0f;

    const int base = blockIdx.x * 64;
    if (base >= n) return;
    const int nt = min(64, n - base);

    for (int i = tid; i < nt * 128; i += 256)
        sx[i >> 7][i & 127] = X[(size_t)base * 128 + i];
    __syncthreads();

    for (int r = sub; r < nt; r += 2) {
        float acc = bf;
        #pragma unroll
        for (int k = 0; k < 128; k += 4) {
            float4 xv = *(const float4*)&sx[r][k];
            acc = fmaf(xv.x, wc[k],     acc);
            acc = fmaf(xv.y, wc[k + 1], acc);
            acc = fmaf(xv.z, wc[k + 2], acc);
            acc = fmaf(xv.w, wc[k + 3], acc);
        }
        size_t o = (size_t)(base + r) * 128 + f;
        if (MODE == 0)      Y[o] = acc;
        else if (MODE == 1) Y[o] = ssp(acc);
        else                Y[o] += acc;
    }
}

// Fused per-molecule edge kernel:
//   for each edge e in molecule m:
//     d = |pos[src]-pos[dst]|; ea[g] = exp(coeff*(d-off_g)^2)
//     t = ssp(ea @ w1 + b1); Wv = (t @ w2 + b2) * cutoff(d)
//     agg[dst] += hx[src] * Wv     (accumulated in LDS, written once)
__global__ __launch_bounds__(256, 2) void edge_kernel(
    const float* __restrict__ pos,
    const int* __restrict__ eidx, int E,
    const float* __restrict__ w1, const float* __restrict__ b1,
    const float* __restrict__ w2, const float* __restrict__ b2,
    const float* __restrict__ hx,
    float* __restrict__ agg)
{
    const int m   = blockIdx.x;            // molecule
    const int tid = threadIdx.x;
    const int f   = tid & 127;
    const int sub = tid >> 7;
    const int* src = eidx;
    const int* dst = eidx + E;

    __shared__ float s_agg[APM][128];      // 16 KB
    __shared__ float s_ea[TE][52];         // 13 KB (pad 50->52)
    __shared__ float s_t[TE][128];         // 32 KB
    __shared__ float s_d[TE];
    __shared__ float s_cut[TE];
    __shared__ int   s_src[TE];
    __shared__ int   s_dl[TE];

    for (int i = tid; i < APM * 128; i += 256) ((float*)s_agg)[i] = 0.0f;

    // per-f weight columns in registers
    float w1c[GDIM], w2c[128];
    #pragma unroll
    for (int g = 0; g < GDIM; g++) w1c[g] = w1[g * 128 + f];
    #pragma unroll
    for (int k = 0; k < 128; k++)  w2c[k] = w2[k * 128 + f];
    const float b1f = b1[f];
    const float b2f = b2[f];

    // binary search edge range of this molecule (src is globally sorted)
    const int v0 = m * APM;
    int lo = 0, hi = E;
    while (lo < hi) { int mid = (lo + hi) >> 1; if (src[mid] < v0) lo = mid + 1; else hi = mid; }
    const int e_start = lo;
    hi = E; const int v1 = v0 + APM;
    while (lo < hi) { int mid = (lo + hi) >> 1; if (src[mid] < v1) lo = mid + 1; else hi = mid; }
    const int e_end = lo;

    const float step  = 6.0f / 49.0f;
    const float coeff = -0.5f / (step * step);
    const float pi_over_cut = 3.14159265358979323846f / 6.0f;

    for (int base = e_start; base < e_end; base += TE) {
        const int nt = min(TE, e_end - base);
        __syncthreads();   // protect shared buffers from previous tile
        if (tid < nt) {
            int e = base + tid;
            int s = src[e], t = dst[e];
            s_src[tid] = s;
            s_dl[tid]  = t - v0;
            float dx = pos[3 * s]     - pos[3 * t];
            float dy = pos[3 * s + 1] - pos[3 * t + 1];
            float dz = pos[3 * s + 2] - pos[3 * t + 2];
            float d  = sqrtf(dx * dx + dy * dy + dz * dz);
            s_d[tid]   = d;
            s_cut[tid] = 0.5f * (cosf(d * pi_over_cut) + 1.0f);
        }
        __syncthreads();
        for (int i = tid; i < nt * GDIM; i += 256) {
            int e = i / GDIM; int g = i - e * GDIM;
            float diff = s_d[e] - (float)g * step;
            s_ea[e][g] = expf(coeff * diff * diff);
        }
        __syncthreads();
        // phase 1: t = ssp(ea @ w1 + b1)
        for (int e = sub; e < nt; e += 2) {
            float acc = b1f;
            #pragma unroll
            for (int g = 0; g < 48; g += 4) {
                float4 a = *(const float4*)&s_ea[e][g];
                acc = fmaf(a.x, w1c[g],     acc);
                acc = fmaf(a.y, w1c[g + 1], acc);
                acc = fmaf(a.z, w1c[g + 2], acc);
                acc = fmaf(a.w, w1c[g + 3], acc);
            }
            acc = fmaf(s_ea[e][48], w1c[48], acc);
            acc = fmaf(s_ea[e][49], w1c[49], acc);
            s_t[e][f] = ssp(acc);
        }
        __syncthreads();
        // phase 2: Wv = (t @ w2 + b2)*cut; msg = hx[src]*Wv; LDS scatter
        for (int e = sub; e < nt; e += 2) {
            float acc = b2f;
            #pragma unroll
            for (int k = 0; k < 128; k += 4) {
                float4 tv = *(const float4*)&s_t[e][k];
                acc = fmaf(tv.x, w2c[k],     acc);
                acc = fmaf(tv.y, w2c[k + 1], acc);
                acc = fmaf(tv.z, w2c[k + 2], acc);
                acc = fmaf(tv.w, w2c[k + 3], acc);
            }
            float Wv  = acc * s_cut[e];
            float msg = hx[(size_t)s_src[e] * 128 + f] * Wv;
            atomicAdd(&s_agg[s_dl[e]][f], msg);
        }
    }
    __syncthreads();
    for (int i = tid; i < APM * 128; i += 256)
        agg[(size_t)v0 * 128 + i] = ((float*)s_agg)[i];
}

// out[m] = sum_a ( ssp(h[m*32+a] @ out1_w + out1_b) @ out2_w + out2_b )
__global__ __launch_bounds__(64) void head_kernel(
    const float* __restrict__ h,
    const float* __restrict__ w1, const float* __restrict__ b1,
    const float* __restrict__ w2, const float* __restrict__ b2,
    float* __restrict__ out)
{
    const int m = blockIdx.x;
    const int f = threadIdx.x;   // 0..63
    float w1c[128];
    #pragma unroll
    for (int k = 0; k < 128; k++) w1c[k] = w1[k * 64 + f];
    const float b1f = b1[f];
    const float w2f = w2[f];
    __shared__ float sh[128];
    float acc = 0.0f;
    for (int a = 0; a < APM; a++) {
        const float* hr = h + (size_t)(m * APM + a) * 128;
        __syncthreads();
        sh[f]      = hr[f];
        sh[f + 64] = hr[f + 64];
        __syncthreads();
        float t = b1f;
        #pragma unroll
        for (int k = 0; k < 128; k += 4) {
            float4 xv = *(const float4*)&sh[k];
            t = fmaf(xv.x, w1c[k],     t);
            t = fmaf(xv.y, w1c[k + 1], t);
            t = fmaf(xv.z, w1c[k + 2], t);
            t = fmaf(xv.w, w1c[k + 3], t);
        }
        acc += ssp(t) * w2f;
    }
    #pragma unroll
    for (int off = 32; off > 0; off >>= 1) acc += __shfl_down(acc, off);
    if (f == 0) out[m] = acc + (float)APM * b2[0];
}

extern "C" void kernel_launch(void* const* d_in, const int* in_sizes, int n_in,
                              void* d_out, int out_size, void* d_ws, size_t ws_size,
                              hipStream_t stream)
{
    const int*   z      = (const int*)d_in[0];
    const float* pos    = (const float*)d_in[1];
    // d_in[2] = batch (implicit: node/32)
    const int*   eidx   = (const int*)d_in[3];
    const float* emb    = (const float*)d_in[4];
    const float* mlp_w1 = (const float*)d_in[5];
    const float* mlp_b1 = (const float*)d_in[6];
    const float* mlp_w2 = (const float*)d_in[7];
    const float* mlp_b2 = (const float*)d_in[8];
    const float* cf1_w  = (const float*)d_in[9];
    const float* cf2_w  = (const float*)d_in[10];
    const float* cf2_b  = (const float*)d_in[11];
    const float* lin_w  = (const float*)d_in[12];
    const float* lin_b  = (const float*)d_in[13];
    const float* out1_w = (const float*)d_in[14];
    const float* out1_b = (const float*)d_in[15];
    const float* out2_w = (const float*)d_in[16];
    const float* out2_b = (const float*)d_in[17];
    const int E = in_sizes[3] / 2;

    float* h   = (float*)d_ws;                     // [N,128]
    float* hx  = h   + (size_t)NATOMS * 128;       // [N,128]
    float* agg = hx  + (size_t)NATOMS * 128;       // [N,128]
    float* t1  = agg + (size_t)NATOMS * 128;       // [N,128]

    embed_kernel<<<(NATOMS * 128) / 256, 256, 0, stream>>>(z, emb, h);

    for (int l = 0; l < 3; l++) {
        gemm128<0><<<NATOMS / 64, 256, 0, stream>>>(
            h, cf1_w + (size_t)l * 128 * 128, nullptr, hx, NATOMS);
        edge_kernel<<<NMOL, 256, 0, stream>>>(
            pos, eidx, E,
            mlp_w1 + (size_t)l * GDIM * 128, mlp_b1 + (size_t)l * 128,
            mlp_w2 + (size_t)l * 128 * 128,  mlp_b2 + (size_t)l * 128,
            hx, agg);
        gemm128<1><<<NATOMS / 64, 256, 0, stream>>>(
            agg, cf2_w + (size_t)l * 128 * 128, cf2_b + (size_t)l * 128, t1, NATOMS);
        gemm128<2><<<NATOMS / 64, 256, 0, stream>>>(
            t1, lin_w + (size_t)l * 128 * 128, lin_b + (size_t)l * 128, h, NATOMS);
    }

    head_kernel<<<NMOL, 64, 0, stream>>>(h, out1_w, out1_b, out2_w, out2_b,
                                         (float*)d_out);
}

// Round 2
// 1271.884 us; speedup vs baseline: 1.9874x; 1.9874x over previous
//
#include <hip/hip_runtime.h>
#include <hip/hip_bf16.h>
#include <math.h>

// Problem constants (SchNet reference)
#define NATOMS 16384
#define NMOL   512
#define APM    32
#define GDIM   50

typedef __attribute__((ext_vector_type(8))) short   short8;   // 8 bf16 (A/B frag)
typedef __attribute__((ext_vector_type(4))) float   floatx4;  // C/D frag

__device__ __forceinline__ float ssp(float x) {
    // shifted softplus: log(1+exp(x)) - log(2)
    return fmaxf(x, 0.0f) + log1pf(expf(-fabsf(x))) - 0.69314718055994531f;
}

__device__ __forceinline__ unsigned short f2bf(float x) {
    // float -> bf16 bits, round-to-nearest-even (inputs never NaN here)
    union { float f; unsigned int u; } v; v.f = x;
    unsigned int lsb = (v.u >> 16) & 1u;
    v.u += 0x7fffu + lsb;
    return (unsigned short)(v.u >> 16);
}

__device__ __forceinline__ float bf2f(unsigned short u) {
    union { unsigned int u; float f; } v; v.u = ((unsigned int)u) << 16;
    return v.f;
}

// h[i][f] = emb[z[i]][f]
__global__ __launch_bounds__(256) void embed_kernel(
    const int* __restrict__ z, const float* __restrict__ emb,
    float* __restrict__ h)
{
    int idx = blockIdx.x * 256 + threadIdx.x;   // over NATOMS*128
    h[idx] = emb[(size_t)z[idx >> 7] * 128 + (idx & 127)];
}

// Y[n][f] = op( sum_k X[n][k] * W[k][f] + b[f] )   (128x128 weight, fp32)
// MODE 0: store, MODE 1: ssp+store, MODE 2: add into Y (residual)
template<int MODE>
__global__ __launch_bounds__(256) void gemm128(
    const float* __restrict__ X, const float* __restrict__ W,
    const float* __restrict__ bias, float* __restrict__ Y, int n)
{
    const int tid = threadIdx.x;
    const int f   = tid & 127;
    const int sub = tid >> 7;
    __shared__ float sx[64][128];

    float wc[128];
    #pragma unroll
    for (int k = 0; k < 128; k++) wc[k] = W[k * 128 + f];
    const float bf = bias ? bias[f] : 0.0f;

    const int base = blockIdx.x * 64;
    if (base >= n) return;
    const int nt = min(64, n - base);

    for (int i = tid; i < nt * 128; i += 256)
        sx[i >> 7][i & 127] = X[(size_t)base * 128 + i];
    __syncthreads();

    for (int r = sub; r < nt; r += 2) {
        float acc = bf;
        #pragma unroll
        for (int k = 0; k < 128; k += 4) {
            float4 xv = *(const float4*)&sx[r][k];
            acc = fmaf(xv.x, wc[k],     acc);
            acc = fmaf(xv.y, wc[k + 1], acc);
            acc = fmaf(xv.z, wc[k + 2], acc);
            acc = fmaf(xv.w, wc[k + 3], acc);
        }
        size_t o = (size_t)(base + r) * 128 + f;
        if (MODE == 0)      Y[o] = acc;
        else if (MODE == 1) Y[o] = ssp(acc);
        else                Y[o] += acc;
    }
}

// ---------------------------------------------------------------------------
// Edge filter kernel (MFMA bf16): W[e][f] = (ssp(ea@w1+b1)@w2 + b2) * cut(d)
// Tile: 64 edges x 128 f per block-iteration; 4 waves, wave w owns edges
// [w*16, w*16+16). A-fragments of edge_attr are computed directly in
// registers (8 exps per K-step per lane) -- edge_attr never touches LDS.
// ---------------------------------------------------------------------------
#define KW1 72    // s_w1T row stride in ushorts ([f][g..64)), 144B = 16B-aligned
#define KW2 136   // s_w2T / s_t row stride in ushorts, 272B = 16B-aligned

__global__ __launch_bounds__(256, 2) void edge_w_kernel(
    const float* __restrict__ pos,
    const int* __restrict__ eidx, int E, int ntiles,
    const float* __restrict__ w1, const float* __restrict__ b1,
    const float* __restrict__ w2, const float* __restrict__ b2,
    unsigned short* __restrict__ Wout)
{
    __shared__ unsigned short s_w1T[128 * KW1];   // [f][g], g padded 50->64
    __shared__ unsigned short s_w2T[128 * KW2];   // [n][k]
    __shared__ unsigned short s_t[64 * KW2];      // [edge][f] bf16
    __shared__ float s_d[64];
    __shared__ float s_cut[64];

    const int tid = threadIdx.x;

    // stage w1 transposed -> bf16 LDS (B-fragment friendly: row n, contiguous k)
    for (int i = tid; i < GDIM * 128; i += 256) {
        int g = i >> 7, f = i & 127;
        s_w1T[f * KW1 + g] = f2bf(w1[i]);
    }
    for (int i = tid; i < (64 - GDIM) * 128; i += 256) {
        int g = GDIM + (i >> 7), f = i & 127;
        s_w1T[f * KW1 + g] = 0;   // zero-pad K 50->64
    }
    for (int i = tid; i < 128 * 128; i += 256) {
        int k = i >> 7, n = i & 127;
        s_w2T[n * KW2 + k] = f2bf(w2[i]);
    }

    const int lane = tid & 63;
    const int w    = tid >> 6;    // wave id, owns edge rows [w*16, w*16+16)
    const int l15  = lane & 15;
    const int quad = lane >> 4;

    float b1v[8], b2v[8];
    #pragma unroll
    for (int nt = 0; nt < 8; nt++) {
        b1v[nt] = b1[nt * 16 + l15];
        b2v[nt] = b2[nt * 16 + l15];
    }

    const float step  = 6.0f / 49.0f;
    const float coeff = -0.5f / (step * step);
    const float pioc  = 3.14159265358979323846f / 6.0f;

    for (int tile = blockIdx.x; tile < ntiles; tile += gridDim.x) {
        const int e0 = tile * 64;
        __syncthreads();   // also covers initial weight staging
        if (tid < 64) {
            int e = e0 + tid;
            float d;
            if (e < E) {
                int s = eidx[e], t = eidx[E + e];
                float dx = pos[3 * s]     - pos[3 * t];
                float dy = pos[3 * s + 1] - pos[3 * t + 1];
                float dz = pos[3 * s + 2] - pos[3 * t + 2];
                d = sqrtf(dx * dx + dy * dy + dz * dz);
            } else d = 1000.0f;   // -> ea = 0, store masked anyway
            s_d[tid]   = d;
            s_cut[tid] = 0.5f * (cosf(d * pioc) + 1.0f);
        }
        __syncthreads();

        const float dm = s_d[w * 16 + l15];   // A-frag row m = lane&15

        // ---- MFMA1: t_pre = ea @ w1, K = 64 (padded), 2 K-steps ----
        floatx4 acc1[8];
        #pragma unroll
        for (int nt = 0; nt < 8; nt++) acc1[nt] = (floatx4){0.f, 0.f, 0.f, 0.f};

        #pragma unroll
        for (int ks = 0; ks < 2; ks++) {
            short8 af;
            #pragma unroll
            for (int j = 0; j < 8; j++) {
                int g = ks * 32 + quad * 8 + j;    // A k-index
                float diff = dm - (float)g * step;
                float v = (g < GDIM) ? __expf(coeff * diff * diff) : 0.0f;
                af[j] = (short)f2bf(v);
            }
            #pragma unroll
            for (int nt = 0; nt < 8; nt++) {
                short8 bfg = *(const short8*)&s_w1T[(nt * 16 + l15) * KW1 + ks * 32 + quad * 8];
                acc1[nt] = __builtin_amdgcn_mfma_f32_16x16x32_bf16(af, bfg, acc1[nt], 0, 0, 0);
            }
        }

        // ssp + bias, write t (bf16) to this wave's own LDS rows
        #pragma unroll
        for (int nt = 0; nt < 8; nt++) {
            #pragma unroll
            for (int r = 0; r < 4; r++) {
                int row = w * 16 + quad * 4 + r;    // D row mapping
                float tv = ssp(acc1[nt][r] + b1v[nt]);
                s_t[row * KW2 + nt * 16 + l15] = f2bf(tv);
            }
        }
        // no __syncthreads: wave reads only rows it wrote (in-order DS + waitcnt)

        // ---- MFMA2: Wv = t @ w2, K = 128, 4 K-steps ----
        floatx4 acc2[8];
        #pragma unroll
        for (int nt = 0; nt < 8; nt++) acc2[nt] = (floatx4){0.f, 0.f, 0.f, 0.f};

        #pragma unroll
        for (int ks = 0; ks < 4; ks++) {
            short8 af = *(const short8*)&s_t[(w * 16 + l15) * KW2 + ks * 32 + quad * 8];
            #pragma unroll
            for (int nt = 0; nt < 8; nt++) {
                short8 bfg = *(const short8*)&s_w2T[(nt * 16 + l15) * KW2 + ks * 32 + quad * 8];
                acc2[nt] = __builtin_amdgcn_mfma_f32_16x16x32_bf16(af, bfg, acc2[nt], 0, 0, 0);
            }
        }

        // epilogue: bias + cosine cutoff, store bf16 W
        #pragma unroll
        for (int nt = 0; nt < 8; nt++) {
            #pragma unroll
            for (int r = 0; r < 4; r++) {
                int row = w * 16 + quad * 4 + r;
                int e = e0 + row;
                if (e < E) {
                    float v = (acc2[nt][r] + b2v[nt]) * s_cut[row];
                    Wout[(size_t)e * 128 + nt * 16 + l15] = f2bf(v);
                }
            }
        }
    }
}

// ---------------------------------------------------------------------------
// Per-molecule scatter: agg[dst] += hx[src] * W[e]   (LDS fp32 accumulation)
// ---------------------------------------------------------------------------
__global__ __launch_bounds__(256, 4) void scatter_kernel(
    const int* __restrict__ eidx, int E,
    const unsigned short* __restrict__ Wb,
    const float* __restrict__ hx,
    float* __restrict__ agg)
{
    const int m   = blockIdx.x;
    const int tid = threadIdx.x;
    const int* src = eidx;
    const int* dst = eidx + E;
    __shared__ float s_agg[APM * 128];   // 16 KB
    for (int i = tid; i < APM * 128; i += 256) s_agg[i] = 0.0f;

    const int v0 = m * APM;
    int lo = 0, hi = E;
    while (lo < hi) { int mid = (lo + hi) >> 1; if (src[mid] < v0) lo = mid + 1; else hi = mid; }
    const int e_start = lo;
    hi = E; const int v1 = v0 + APM;
    while (lo < hi) { int mid = (lo + hi) >> 1; if (src[mid] < v1) lo = mid + 1; else hi = mid; }
    const int e_end = lo;
    __syncthreads();

    const int sub = tid >> 5;   // 8 edges in flight
    const int l32 = tid & 31;
    for (int e = e_start + sub; e < e_end; e += 8) {
        int s  = src[e];
        int dl = dst[e] - v0;
        #pragma unroll
        for (int k2 = 0; k2 < 2; k2++) {
            int f = 2 * l32 + 64 * k2;
            unsigned int wp = *(const unsigned int*)&Wb[(size_t)e * 128 + f];
            float2 hv = *(const float2*)&hx[(size_t)s * 128 + f];
            atomicAdd(&s_agg[dl * 128 + f],     hv.x * bf2f((unsigned short)(wp & 0xffffu)));
            atomicAdd(&s_agg[dl * 128 + f + 1], hv.y * bf2f((unsigned short)(wp >> 16)));
        }
    }
    __syncthreads();
    for (int i = tid; i < APM * 128; i += 256)
        agg[(size_t)v0 * 128 + i] = s_agg[i];
}

// out[m] = sum_a ( ssp(h[m*32+a] @ out1_w + out1_b) @ out2_w + out2_b )
__global__ __launch_bounds__(64) void head_kernel(
    const float* __restrict__ h,
    const float* __restrict__ w1, const float* __restrict__ b1,
    const float* __restrict__ w2, const float* __restrict__ b2,
    float* __restrict__ out)
{
    const int m = blockIdx.x;
    const int f = threadIdx.x;   // 0..63
    float w1c[128];
    #pragma unroll
    for (int k = 0; k < 128; k++) w1c[k] = w1[k * 64 + f];
    const float b1f = b1[f];
    const float w2f = w2[f];
    __shared__ float sh[128];
    float acc = 0.0f;
    for (int a = 0; a < APM; a++) {
        const float* hr = h + (size_t)(m * APM + a) * 128;
        __syncthreads();
        sh[f]      = hr[f];
        sh[f + 64] = hr[f + 64];
        __syncthreads();
        float t = b1f;
        #pragma unroll
        for (int k = 0; k < 128; k += 4) {
            float4 xv = *(const float4*)&sh[k];
            t = fmaf(xv.x, w1c[k],     t);
            t = fmaf(xv.y, w1c[k + 1], t);
            t = fmaf(xv.z, w1c[k + 2], t);
            t = fmaf(xv.w, w1c[k + 3], t);
        }
        acc += ssp(t) * w2f;
    }
    #pragma unroll
    for (int off = 32; off > 0; off >>= 1) acc += __shfl_down(acc, off);
    if (f == 0) out[m] = acc + (float)APM * b2[0];
}

extern "C" void kernel_launch(void* const* d_in, const int* in_sizes, int n_in,
                              void* d_out, int out_size, void* d_ws, size_t ws_size,
                              hipStream_t stream)
{
    const int*   z      = (const int*)d_in[0];
    const float* pos    = (const float*)d_in[1];
    const int*   eidx   = (const int*)d_in[3];
    const float* emb    = (const float*)d_in[4];
    const float* mlp_w1 = (const float*)d_in[5];
    const float* mlp_b1 = (const float*)d_in[6];
    const float* mlp_w2 = (const float*)d_in[7];
    const float* mlp_b2 = (const float*)d_in[8];
    const float* cf1_w  = (const float*)d_in[9];
    const float* cf2_w  = (const float*)d_in[10];
    const float* cf2_b  = (const float*)d_in[11];
    const float* lin_w  = (const float*)d_in[12];
    const float* lin_b  = (const float*)d_in[13];
    const float* out1_w = (const float*)d_in[14];
    const float* out1_b = (const float*)d_in[15];
    const float* out2_w = (const float*)d_in[16];
    const float* out2_b = (const float*)d_in[17];
    const int E = in_sizes[3] / 2;
    const int ntiles = (E + 63) / 64;

    float* h   = (float*)d_ws;                        // [N,128]
    float* hx  = h   + (size_t)NATOMS * 128;          // [N,128] (also t1, aliased)
    float* agg = hx  + (size_t)NATOMS * 128;          // [N,128]
    unsigned short* Wb = (unsigned short*)(agg + (size_t)NATOMS * 128);  // [E,128] bf16

    embed_kernel<<<(NATOMS * 128) / 256, 256, 0, stream>>>(z, emb, h);

    const int wgrid = ntiles < 512 ? ntiles : 512;
    for (int l = 0; l < 3; l++) {
        gemm128<0><<<NATOMS / 64, 256, 0, stream>>>(
            h, cf1_w + (size_t)l * 128 * 128, nullptr, hx, NATOMS);
        edge_w_kernel<<<wgrid, 256, 0, stream>>>(
            pos, eidx, E, ntiles,
            mlp_w1 + (size_t)l * GDIM * 128, mlp_b1 + (size_t)l * 128,
            mlp_w2 + (size_t)l * 128 * 128,  mlp_b2 + (size_t)l * 128,
            Wb);
        scatter_kernel<<<NMOL, 256, 0, stream>>>(eidx, E, Wb, hx, agg);
        gemm128<1><<<NATOMS / 64, 256, 0, stream>>>(
            agg, cf2_w + (size_t)l * 128 * 128, cf2_b + (size_t)l * 128, hx, NATOMS);
        gemm128<2><<<NATOMS / 64, 256, 0, stream>>>(
            hx, lin_w + (size_t)l * 128 * 128, lin_b + (size_t)l * 128, h, NATOMS);
    }

    head_kernel<<<NMOL, 64, 0, stream>>>(h, out1_w, out1_b, out2_w, out2_b,
                                         (float*)d_out);
}

// Round 3
// 1051.139 us; speedup vs baseline: 2.4048x; 1.2100x over previous
//
#include <hip/hip_runtime.h>
#include <hip/hip_bf16.h>
#include <math.h>

// Problem constants (SchNet reference)
#define NATOMS 16384
#define NMOL   512
#define APM    32
#define GDIM   50

typedef __attribute__((ext_vector_type(8))) short   short8;   // 8 bf16 (A/B frag)
typedef __attribute__((ext_vector_type(4))) float   floatx4;  // C/D frag

__device__ __forceinline__ float ssp(float x) {
    // shifted softplus: log(1+exp(x)) - log(2)
    return fmaxf(x, 0.0f) + log1pf(expf(-fabsf(x))) - 0.69314718055994531f;
}

__device__ __forceinline__ unsigned short f2bf(float x) {
    // float -> bf16 bits, round-to-nearest-even (inputs never NaN here)
    union { float f; unsigned int u; } v; v.f = x;
    unsigned int lsb = (v.u >> 16) & 1u;
    v.u += 0x7fffu + lsb;
    return (unsigned short)(v.u >> 16);
}

__device__ __forceinline__ float bf2f(unsigned short u) {
    union { unsigned int u; float f; } v; v.u = ((unsigned int)u) << 16;
    return v.f;
}

// h[i][f] = emb[z[i]][f]
__global__ __launch_bounds__(256) void embed_kernel(
    const int* __restrict__ z, const float* __restrict__ emb,
    float* __restrict__ h)
{
    int idx = blockIdx.x * 256 + threadIdx.x;   // over NATOMS*128
    h[idx] = emb[(size_t)z[idx >> 7] * 128 + (idx & 127)];
}

// rowptr[a] = lower_bound(src, a)  for a in [0, NATOMS]  (src globally sorted)
__global__ __launch_bounds__(256) void rowptr_kernel(
    const int* __restrict__ src, int E, int* __restrict__ rowptr)
{
    int a = blockIdx.x * 256 + threadIdx.x;
    if (a > NATOMS) return;
    int lo = 0, hi = E;
    while (lo < hi) { int mid = (lo + hi) >> 1; if (src[mid] < a) lo = mid + 1; else hi = mid; }
    rowptr[a] = lo;
}

// Y[n][f] = op( sum_k X[n][k] * W[k][f] + b[f] )   (128x128 weight, fp32)
// MODE 0: store, MODE 1: ssp+store, MODE 2: add into Y (residual)
template<int MODE>
__global__ __launch_bounds__(256, 2) void gemm128(
    const float* __restrict__ X, const float* __restrict__ W,
    const float* __restrict__ bias, float* __restrict__ Y, int n)
{
    const int tid = threadIdx.x;
    const int f   = tid & 127;
    const int sub = tid >> 7;
    __shared__ float sx[32][128];

    float wc[128];
    #pragma unroll
    for (int k = 0; k < 128; k++) wc[k] = W[k * 128 + f];
    const float bf = bias ? bias[f] : 0.0f;

    const int base = blockIdx.x * 32;
    if (base >= n) return;
    const int nt = min(32, n - base);

    for (int i = tid; i < nt * 128; i += 256)
        sx[i >> 7][i & 127] = X[(size_t)base * 128 + i];
    __syncthreads();

    for (int r = sub; r < nt; r += 2) {
        float acc = bf;
        #pragma unroll
        for (int k = 0; k < 128; k += 4) {
            float4 xv = *(const float4*)&sx[r][k];
            acc = fmaf(xv.x, wc[k],     acc);
            acc = fmaf(xv.y, wc[k + 1], acc);
            acc = fmaf(xv.z, wc[k + 2], acc);
            acc = fmaf(xv.w, wc[k + 3], acc);
        }
        size_t o = (size_t)(base + r) * 128 + f;
        if (MODE == 0)      Y[o] = acc;
        else if (MODE == 1) Y[o] = ssp(acc);
        else                Y[o] += acc;
    }
}

// ---------------------------------------------------------------------------
// Edge filter kernel (MFMA bf16): W[e][f] = (ssp(ea@w1+b1)@w2 + b2) * cut(d)
// Tile: 64 edges x 128 f per block-iteration; 4 waves, wave w owns edges
// [w*16, w*16+16). A-fragments of edge_attr are computed directly in
// registers (8 exps per K-step per lane) -- edge_attr never touches LDS.
// ---------------------------------------------------------------------------
#define KW1 72    // s_w1T row stride in ushorts ([f][g..64)), 144B = 16B-aligned
#define KW2 136   // s_w2T / s_t row stride in ushorts, 272B = 16B-aligned

__global__ __launch_bounds__(256, 2) void edge_w_kernel(
    const float* __restrict__ pos,
    const int* __restrict__ eidx, int E, int ntiles,
    const float* __restrict__ w1, const float* __restrict__ b1,
    const float* __restrict__ w2, const float* __restrict__ b2,
    unsigned short* __restrict__ Wout)
{
    __shared__ unsigned short s_w1T[128 * KW1];   // [f][g], g padded 50->64
    __shared__ unsigned short s_w2T[128 * KW2];   // [n][k]
    __shared__ unsigned short s_t[64 * KW2];      // [edge][f] bf16
    __shared__ float s_d[64];
    __shared__ float s_cut[64];

    const int tid = threadIdx.x;

    // stage w1 transposed -> bf16 LDS (B-fragment friendly: row n, contiguous k)
    for (int i = tid; i < GDIM * 128; i += 256) {
        int g = i >> 7, f = i & 127;
        s_w1T[f * KW1 + g] = f2bf(w1[i]);
    }
    for (int i = tid; i < (64 - GDIM) * 128; i += 256) {
        int g = GDIM + (i >> 7), f = i & 127;
        s_w1T[f * KW1 + g] = 0;   // zero-pad K 50->64
    }
    for (int i = tid; i < 128 * 128; i += 256) {
        int k = i >> 7, n = i & 127;
        s_w2T[n * KW2 + k] = f2bf(w2[i]);
    }

    const int lane = tid & 63;
    const int w    = tid >> 6;    // wave id, owns edge rows [w*16, w*16+16)
    const int l15  = lane & 15;
    const int quad = lane >> 4;

    float b1v[8], b2v[8];
    #pragma unroll
    for (int nt = 0; nt < 8; nt++) {
        b1v[nt] = b1[nt * 16 + l15];
        b2v[nt] = b2[nt * 16 + l15];
    }

    const float step  = 6.0f / 49.0f;
    const float coeff = -0.5f / (step * step);
    const float pioc  = 3.14159265358979323846f / 6.0f;

    for (int tile = blockIdx.x; tile < ntiles; tile += gridDim.x) {
        const int e0 = tile * 64;
        __syncthreads();   // also covers initial weight staging
        if (tid < 64) {
            int e = e0 + tid;
            float d;
            if (e < E) {
                int s = eidx[e], t = eidx[E + e];
                float dx = pos[3 * s]     - pos[3 * t];
                float dy = pos[3 * s + 1] - pos[3 * t + 1];
                float dz = pos[3 * s + 2] - pos[3 * t + 2];
                d = sqrtf(dx * dx + dy * dy + dz * dz);
            } else d = 1000.0f;   // -> ea = 0, store masked anyway
            s_d[tid]   = d;
            s_cut[tid] = 0.5f * (cosf(d * pioc) + 1.0f);
        }
        __syncthreads();

        const float dm = s_d[w * 16 + l15];   // A-frag row m = lane&15

        // ---- MFMA1: t_pre = ea @ w1, K = 64 (padded), 2 K-steps ----
        floatx4 acc1[8];
        #pragma unroll
        for (int nt = 0; nt < 8; nt++) acc1[nt] = (floatx4){0.f, 0.f, 0.f, 0.f};

        #pragma unroll
        for (int ks = 0; ks < 2; ks++) {
            short8 af;
            #pragma unroll
            for (int j = 0; j < 8; j++) {
                int g = ks * 32 + quad * 8 + j;    // A k-index
                float diff = dm - (float)g * step;
                float v = (g < GDIM) ? __expf(coeff * diff * diff) : 0.0f;
                af[j] = (short)f2bf(v);
            }
            #pragma unroll
            for (int nt = 0; nt < 8; nt++) {
                short8 bfg = *(const short8*)&s_w1T[(nt * 16 + l15) * KW1 + ks * 32 + quad * 8];
                acc1[nt] = __builtin_amdgcn_mfma_f32_16x16x32_bf16(af, bfg, acc1[nt], 0, 0, 0);
            }
        }

        // ssp + bias, write t (bf16) to this wave's own LDS rows
        #pragma unroll
        for (int nt = 0; nt < 8; nt++) {
            #pragma unroll
            for (int r = 0; r < 4; r++) {
                int row = w * 16 + quad * 4 + r;    // D row mapping
                float tv = ssp(acc1[nt][r] + b1v[nt]);
                s_t[row * KW2 + nt * 16 + l15] = f2bf(tv);
            }
        }
        // no __syncthreads: wave reads only rows it wrote (in-order DS + waitcnt)

        // ---- MFMA2: Wv = t @ w2, K = 128, 4 K-steps ----
        floatx4 acc2[8];
        #pragma unroll
        for (int nt = 0; nt < 8; nt++) acc2[nt] = (floatx4){0.f, 0.f, 0.f, 0.f};

        #pragma unroll
        for (int ks = 0; ks < 4; ks++) {
            short8 af = *(const short8*)&s_t[(w * 16 + l15) * KW2 + ks * 32 + quad * 8];
            #pragma unroll
            for (int nt = 0; nt < 8; nt++) {
                short8 bfg = *(const short8*)&s_w2T[(nt * 16 + l15) * KW2 + ks * 32 + quad * 8];
                acc2[nt] = __builtin_amdgcn_mfma_f32_16x16x32_bf16(af, bfg, acc2[nt], 0, 0, 0);
            }
        }

        // epilogue: bias + cosine cutoff, store bf16 W
        #pragma unroll
        for (int nt = 0; nt < 8; nt++) {
            #pragma unroll
            for (int r = 0; r < 4; r++) {
                int row = w * 16 + quad * 4 + r;
                int e = e0 + row;
                if (e < E) {
                    float v = (acc2[nt][r] + b2v[nt]) * s_cut[row];
                    Wout[(size_t)e * 128 + nt * 16 + l15] = f2bf(v);
                }
            }
        }
    }
}

// ---------------------------------------------------------------------------
// Symmetric gather: agg[a][f] = sum_{e in [rowptr[a],rowptr[a+1])}
//                              hx[dst[e]][f] * W[e][f]
// Valid because the radius graph is symmetric and W[(s,t)] == W[(t,s)]
// (W depends only on d, which is symmetric; identical inputs -> identical
// MFMA outputs bit-for-bit). No atomics, no LDS; 16 atoms per block.
// ---------------------------------------------------------------------------
__global__ __launch_bounds__(256) void gather_kernel(
    const int* __restrict__ dst, const int* __restrict__ rowptr,
    const unsigned short* __restrict__ Wb,
    const float* __restrict__ hx,
    float* __restrict__ agg)
{
    const int tid = threadIdx.x;
    const int f   = tid & 127;
    const int sub = tid >> 7;
    const int a0  = blockIdx.x * 16;

    for (int r = sub; r < 16; r += 2) {
        const int a  = a0 + r;
        const int e0 = rowptr[a];
        const int e1 = rowptr[a + 1];
        float acc0 = 0.0f, acc1 = 0.0f;
        int e = e0;
        for (; e + 1 < e1; e += 2) {
            int t0 = dst[e], t1 = dst[e + 1];
            float w0 = bf2f(Wb[(size_t)e * 128 + f]);
            float w1 = bf2f(Wb[(size_t)(e + 1) * 128 + f]);
            acc0 = fmaf(hx[(size_t)t0 * 128 + f], w0, acc0);
            acc1 = fmaf(hx[(size_t)t1 * 128 + f], w1, acc1);
        }
        if (e < e1) {
            int t0 = dst[e];
            acc0 = fmaf(hx[(size_t)t0 * 128 + f], bf2f(Wb[(size_t)e * 128 + f]), acc0);
        }
        agg[(size_t)a * 128 + f] = acc0 + acc1;
    }
}

// out[m] = sum_a ( ssp(h[m*32+a] @ out1_w + out1_b) @ out2_w + out2_b )
__global__ __launch_bounds__(64) void head_kernel(
    const float* __restrict__ h,
    const float* __restrict__ w1, const float* __restrict__ b1,
    const float* __restrict__ w2, const float* __restrict__ b2,
    float* __restrict__ out)
{
    const int m = blockIdx.x;
    const int f = threadIdx.x;   // 0..63
    float w1c[128];
    #pragma unroll
    for (int k = 0; k < 128; k++) w1c[k] = w1[k * 64 + f];
    const float b1f = b1[f];
    const float w2f = w2[f];
    __shared__ float sh[128];
    float acc = 0.0f;
    for (int a = 0; a < APM; a++) {
        const float* hr = h + (size_t)(m * APM + a) * 128;
        __syncthreads();
        sh[f]      = hr[f];
        sh[f + 64] = hr[f + 64];
        __syncthreads();
        float t = b1f;
        #pragma unroll
        for (int k = 0; k < 128; k += 4) {
            float4 xv = *(const float4*)&sh[k];
            t = fmaf(xv.x, w1c[k],     t);
            t = fmaf(xv.y, w1c[k + 1], t);
            t = fmaf(xv.z, w1c[k + 2], t);
            t = fmaf(xv.w, w1c[k + 3], t);
        }
        acc += ssp(t) * w2f;
    }
    #pragma unroll
    for (int off = 32; off > 0; off >>= 1) acc += __shfl_down(acc, off);
    if (f == 0) out[m] = acc + (float)APM * b2[0];
}

extern "C" void kernel_launch(void* const* d_in, const int* in_sizes, int n_in,
                              void* d_out, int out_size, void* d_ws, size_t ws_size,
                              hipStream_t stream)
{
    const int*   z      = (const int*)d_in[0];
    const float* pos    = (const float*)d_in[1];
    const int*   eidx   = (const int*)d_in[3];
    const float* emb    = (const float*)d_in[4];
    const float* mlp_w1 = (const float*)d_in[5];
    const float* mlp_b1 = (const float*)d_in[6];
    const float* mlp_w2 = (const float*)d_in[7];
    const float* mlp_b2 = (const float*)d_in[8];
    const float* cf1_w  = (const float*)d_in[9];
    const float* cf2_w  = (const float*)d_in[10];
    const float* cf2_b  = (const float*)d_in[11];
    const float* lin_w  = (const float*)d_in[12];
    const float* lin_b  = (const float*)d_in[13];
    const float* out1_w = (const float*)d_in[14];
    const float* out1_b = (const float*)d_in[15];
    const float* out2_w = (const float*)d_in[16];
    const float* out2_b = (const float*)d_in[17];
    const int E = in_sizes[3] / 2;
    const int ntiles = (E + 63) / 64;

    float* h   = (float*)d_ws;                        // [N,128]
    float* hx  = h   + (size_t)NATOMS * 128;          // [N,128]
    float* agg = hx  + (size_t)NATOMS * 128;          // [N,128]
    unsigned short* Wb = (unsigned short*)(agg + (size_t)NATOMS * 128);  // [E,128] bf16
    int* rowptr = (int*)(Wb + (size_t)E * 128);       // [NATOMS+1]

    embed_kernel<<<(NATOMS * 128) / 256, 256, 0, stream>>>(z, emb, h);
    rowptr_kernel<<<(NATOMS + 256) / 256, 256, 0, stream>>>(eidx, E, rowptr);

    const int wgrid = ntiles < 512 ? ntiles : 512;
    for (int l = 0; l < 3; l++) {
        gemm128<0><<<NATOMS / 32, 256, 0, stream>>>(
            h, cf1_w + (size_t)l * 128 * 128, nullptr, hx, NATOMS);
        edge_w_kernel<<<wgrid, 256, 0, stream>>>(
            pos, eidx, E, ntiles,
            mlp_w1 + (size_t)l * GDIM * 128, mlp_b1 + (size_t)l * 128,
            mlp_w2 + (size_t)l * 128 * 128,  mlp_b2 + (size_t)l * 128,
            Wb);
        gather_kernel<<<NATOMS / 16, 256, 0, stream>>>(eidx + E, rowptr, Wb, hx, agg);
        gemm128<1><<<NATOMS / 32, 256, 0, stream>>>(
            agg, cf2_w + (size_t)l * 128 * 128, cf2_b + (size_t)l * 128, hx, NATOMS);
        gemm128<2><<<NATOMS / 32, 256, 0, stream>>>(
            hx, lin_w + (size_t)l * 128 * 128, lin_b + (size_t)l * 128, h, NATOMS);
    }

    head_kernel<<<NMOL, 64, 0, stream>>>(h, out1_w, out1_b, out2_w, out2_b,
                                         (float*)d_out);
}

// Round 4
// 491.552 us; speedup vs baseline: 5.1423x; 2.1384x over previous
//
#include <hip/hip_runtime.h>
#include <hip/hip_bf16.h>
#include <math.h>

// Problem constants (SchNet reference)
#define NATOMS 16384
#define NMOL   512
#define APM    32
#define GDIM   50

typedef __attribute__((ext_vector_type(8))) short   short8;   // 8 bf16 (A/B frag)
typedef __attribute__((ext_vector_type(4))) float   floatx4;  // C/D frag

// fast shifted softplus: log(1+exp(x)) - log2, via HW v_exp_f32/v_log_f32
__device__ __forceinline__ float ssp(float x) {
    float e = __expf(-fabsf(x));
    return fmaxf(x, 0.0f) + __logf(1.0f + e) - 0.69314718055994531f;
}

__device__ __forceinline__ unsigned short f2bf(float x) {
    union { float f; unsigned int u; } v; v.f = x;
    unsigned int lsb = (v.u >> 16) & 1u;
    v.u += 0x7fffu + lsb;
    return (unsigned short)(v.u >> 16);
}

__device__ __forceinline__ unsigned int pk2bf(float a, float b) {
    // packed fp32x2 -> bf16x2 (v_cvt_pk_bf16_f32 on gfx950)
    __hip_bfloat162 h = __float22bfloat162_rn(make_float2(a, b));
    unsigned int u;
    __builtin_memcpy(&u, &h, 4);
    return u;
}

__device__ __forceinline__ float bf2f(unsigned short u) {
    union { unsigned int u; float f; } v; v.u = ((unsigned int)u) << 16;
    return v.f;
}

// h[i][f] = emb[z[i]][f]
__global__ __launch_bounds__(256) void embed_kernel(
    const int* __restrict__ z, const float* __restrict__ emb,
    float* __restrict__ h)
{
    int idx = blockIdx.x * 256 + threadIdx.x;   // over NATOMS*128
    h[idx] = emb[(size_t)z[idx >> 7] * 128 + (idx & 127)];
}

// rowptr[a] = lower_bound(src, a)  for a in [0, NATOMS]  (src globally sorted)
__global__ __launch_bounds__(256) void rowptr_kernel(
    const int* __restrict__ src, int E, int* __restrict__ rowptr)
{
    int a = blockIdx.x * 256 + threadIdx.x;
    if (a > NATOMS) return;
    int lo = 0, hi = E;
    while (lo < hi) { int mid = (lo + hi) >> 1; if (src[mid] < a) lo = mid + 1; else hi = mid; }
    rowptr[a] = lo;
}

// Pre-convert the 9 node-GEMM weights [k][n] fp32 -> [n][k] bf16 (B-frag layout)
// wi = layer*3 + {0:cf1, 1:cf2, 2:lin}
__global__ __launch_bounds__(256) void prep_weights_kernel(
    const float* __restrict__ cf1, const float* __restrict__ cf2,
    const float* __restrict__ lin, unsigned short* __restrict__ Wtall)
{
    int idx = blockIdx.x * 256 + threadIdx.x;     // over 9*128*128
    if (idx >= 9 * 16384) return;
    int wi = idx >> 14, rem = idx & 16383;
    int n = rem >> 7, k = rem & 127;
    int l = wi / 3, which = wi % 3;
    const float* src = (which == 0) ? cf1 : (which == 1) ? cf2 : lin;
    Wtall[idx] = f2bf(src[(size_t)l * 16384 + k * 128 + n]);
}

// ---------------------------------------------------------------------------
// Node GEMM via MFMA bf16: Y[n][f] = op( X[n][:] @ W + b )
// Block: 256 thr = 4 waves, 64 rows x 128 cols. Wave w owns rows w*16..+16.
// X staged fp32->bf16 in LDS; B-frags read from pre-converted global (L2-hot).
// MODE 0: store, MODE 1: ssp+store, MODE 2: add into Y (residual)
// ---------------------------------------------------------------------------
template<int MODE>
__global__ __launch_bounds__(256, 2) void gemm_mfma(
    const float* __restrict__ X, const unsigned short* __restrict__ Wt,
    const float* __restrict__ bias, float* __restrict__ Y)
{
    __shared__ unsigned short s_x[64 * 136];   // [row][k], 272B row stride
    const int tid  = threadIdx.x;
    const int lane = tid & 63;
    const int w    = tid >> 6;
    const int l15  = lane & 15;
    const int quad = lane >> 4;
    const int base = blockIdx.x * 64;

    // stage X tile -> bf16 LDS (packed cvt, 16B LDS writes)
    #pragma unroll
    for (int it = 0; it < 4; it++) {
        int idx = it * 2048 + tid * 8;
        const float4 xa = *(const float4*)&X[(size_t)base * 128 + idx];
        const float4 xb = *(const float4*)&X[(size_t)base * 128 + idx + 4];
        int row = idx >> 7, col = idx & 127;
        unsigned int p[4];
        p[0] = pk2bf(xa.x, xa.y); p[1] = pk2bf(xa.z, xa.w);
        p[2] = pk2bf(xb.x, xb.y); p[3] = pk2bf(xb.z, xb.w);
        __builtin_memcpy(&s_x[row * 136 + col], p, 16);
    }

    float bv[8];
    #pragma unroll
    for (int nt = 0; nt < 8; nt++) bv[nt] = bias ? bias[nt * 16 + l15] : 0.0f;

    __syncthreads();

    floatx4 acc[8];
    #pragma unroll
    for (int nt = 0; nt < 8; nt++) acc[nt] = (floatx4){0.f, 0.f, 0.f, 0.f};

    #pragma unroll
    for (int ks = 0; ks < 4; ks++) {
        short8 af = *(const short8*)&s_x[(w * 16 + l15) * 136 + ks * 32 + quad * 8];
        #pragma unroll
        for (int nt = 0; nt < 8; nt++) {
            short8 bfg = *(const short8*)&Wt[(size_t)(nt * 16 + l15) * 128 + ks * 32 + quad * 8];
            acc[nt] = __builtin_amdgcn_mfma_f32_16x16x32_bf16(af, bfg, acc[nt], 0, 0, 0);
        }
    }

    #pragma unroll
    for (int nt = 0; nt < 8; nt++) {
        #pragma unroll
        for (int r = 0; r < 4; r++) {
            int row = w * 16 + quad * 4 + r;
            size_t o = (size_t)(base + row) * 128 + nt * 16 + l15;
            float v = acc[nt][r] + bv[nt];
            if (MODE == 0)      Y[o] = v;
            else if (MODE == 1) Y[o] = ssp(v);
            else                Y[o] += v;
        }
    }
}

// ---------------------------------------------------------------------------
// Edge filter kernel (MFMA bf16): W[e][f] = (ssp(ea@w1+b1)@w2 + b2) * cut(d)
// ---------------------------------------------------------------------------
#define KW1 72    // s_w1T row stride in ushorts
#define KW2 136   // s_w2T / s_t row stride in ushorts

__global__ __launch_bounds__(256, 2) void edge_w_kernel(
    const float* __restrict__ pos,
    const int* __restrict__ eidx, int E, int ntiles,
    const float* __restrict__ w1, const float* __restrict__ b1,
    const float* __restrict__ w2, const float* __restrict__ b2,
    unsigned short* __restrict__ Wout)
{
    __shared__ unsigned short s_w1T[128 * KW1];   // [f][g], g padded 50->64
    __shared__ unsigned short s_w2T[128 * KW2];   // [n][k]
    __shared__ unsigned short s_t[64 * KW2];      // [edge][f] bf16
    __shared__ float s_d[64];
    __shared__ float s_cut[64];

    const int tid = threadIdx.x;

    for (int i = tid; i < GDIM * 128; i += 256) {
        int g = i >> 7, f = i & 127;
        s_w1T[f * KW1 + g] = f2bf(w1[i]);
    }
    for (int i = tid; i < (64 - GDIM) * 128; i += 256) {
        int g = GDIM + (i >> 7), f = i & 127;
        s_w1T[f * KW1 + g] = 0;
    }
    for (int i = tid; i < 128 * 128; i += 256) {
        int k = i >> 7, n = i & 127;
        s_w2T[n * KW2 + k] = f2bf(w2[i]);
    }

    const int lane = tid & 63;
    const int w    = tid >> 6;
    const int l15  = lane & 15;
    const int quad = lane >> 4;

    float b1v[8], b2v[8];
    #pragma unroll
    for (int nt = 0; nt < 8; nt++) {
        b1v[nt] = b1[nt * 16 + l15];
        b2v[nt] = b2[nt * 16 + l15];
    }

    const float step  = 6.0f / 49.0f;
    const float coeff = -0.5f / (step * step);
    const float pioc  = 3.14159265358979323846f / 6.0f;

    for (int tile = blockIdx.x; tile < ntiles; tile += gridDim.x) {
        const int e0 = tile * 64;
        __syncthreads();
        if (tid < 64) {
            int e = e0 + tid;
            float d;
            if (e < E) {
                int s = eidx[e], t = eidx[E + e];
                float dx = pos[3 * s]     - pos[3 * t];
                float dy = pos[3 * s + 1] - pos[3 * t + 1];
                float dz = pos[3 * s + 2] - pos[3 * t + 2];
                d = sqrtf(dx * dx + dy * dy + dz * dz);
            } else d = 1000.0f;
            s_d[tid]   = d;
            s_cut[tid] = 0.5f * (__cosf(d * pioc) + 1.0f);
        }
        __syncthreads();

        const float dm = s_d[w * 16 + l15];

        // ---- MFMA1: t_pre = ea @ w1, K = 64 (padded), 2 K-steps ----
        floatx4 acc1[8];
        #pragma unroll
        for (int nt = 0; nt < 8; nt++) acc1[nt] = (floatx4){0.f, 0.f, 0.f, 0.f};

        #pragma unroll
        for (int ks = 0; ks < 2; ks++) {
            unsigned int ap[4];
            #pragma unroll
            for (int jj = 0; jj < 4; jj++) {
                int g0 = ks * 32 + quad * 8 + 2 * jj;
                float d0 = dm - (float)g0 * step;
                float d1 = dm - (float)(g0 + 1) * step;
                float v0 = (g0 < GDIM)     ? __expf(coeff * d0 * d0) : 0.0f;
                float v1 = (g0 + 1 < GDIM) ? __expf(coeff * d1 * d1) : 0.0f;
                ap[jj] = pk2bf(v0, v1);
            }
            short8 af;
            __builtin_memcpy(&af, ap, 16);
            #pragma unroll
            for (int nt = 0; nt < 8; nt++) {
                short8 bfg = *(const short8*)&s_w1T[(nt * 16 + l15) * KW1 + ks * 32 + quad * 8];
                acc1[nt] = __builtin_amdgcn_mfma_f32_16x16x32_bf16(af, bfg, acc1[nt], 0, 0, 0);
            }
        }

        // ssp + bias, write t (bf16) to this wave's own LDS rows
        #pragma unroll
        for (int nt = 0; nt < 8; nt++) {
            #pragma unroll
            for (int r = 0; r < 4; r++) {
                int row = w * 16 + quad * 4 + r;
                float tv = ssp(acc1[nt][r] + b1v[nt]);
                s_t[row * KW2 + nt * 16 + l15] = f2bf(tv);
            }
        }
        // no __syncthreads: wave reads only rows it wrote

        // ---- MFMA2: Wv = t @ w2, K = 128, 4 K-steps ----
        floatx4 acc2[8];
        #pragma unroll
        for (int nt = 0; nt < 8; nt++) acc2[nt] = (floatx4){0.f, 0.f, 0.f, 0.f};

        #pragma unroll
        for (int ks = 0; ks < 4; ks++) {
            short8 af = *(const short8*)&s_t[(w * 16 + l15) * KW2 + ks * 32 + quad * 8];
            #pragma unroll
            for (int nt = 0; nt < 8; nt++) {
                short8 bfg = *(const short8*)&s_w2T[(nt * 16 + l15) * KW2 + ks * 32 + quad * 8];
                acc2[nt] = __builtin_amdgcn_mfma_f32_16x16x32_bf16(af, bfg, acc2[nt], 0, 0, 0);
            }
        }

        // epilogue: bias + cosine cutoff, store bf16 W
        #pragma unroll
        for (int nt = 0; nt < 8; nt++) {
            #pragma unroll
            for (int r = 0; r < 4; r++) {
                int row = w * 16 + quad * 4 + r;
                int e = e0 + row;
                if (e < E) {
                    float v = (acc2[nt][r] + b2v[nt]) * s_cut[row];
                    Wout[(size_t)e * 128 + nt * 16 + l15] = f2bf(v);
                }
            }
        }
    }
}

// ---------------------------------------------------------------------------
// Symmetric gather: agg[a][f] = sum_e hx[dst[e]][f] * W[e][f]
// (radius graph symmetric; W[(s,t)]==W[(t,s)] bit-identically)
// ---------------------------------------------------------------------------
__global__ __launch_bounds__(256) void gather_kernel(
    const int* __restrict__ dst, const int* __restrict__ rowptr,
    const unsigned short* __restrict__ Wb,
    const float* __restrict__ hx,
    float* __restrict__ agg)
{
    const int tid = threadIdx.x;
    const int f   = tid & 127;
    const int sub = tid >> 7;
    const int a0  = blockIdx.x * 16;

    for (int r = sub; r < 16; r += 2) {
        const int a  = a0 + r;
        const int e0 = rowptr[a];
        const int e1 = rowptr[a + 1];
        float acc0 = 0.0f, acc1 = 0.0f;
        int e = e0;
        for (; e + 1 < e1; e += 2) {
            int t0 = dst[e], t1 = dst[e + 1];
            float w0 = bf2f(Wb[(size_t)e * 128 + f]);
            float w1 = bf2f(Wb[(size_t)(e + 1) * 128 + f]);
            acc0 = fmaf(hx[(size_t)t0 * 128 + f], w0, acc0);
            acc1 = fmaf(hx[(size_t)t1 * 128 + f], w1, acc1);
        }
        if (e < e1) {
            int t0 = dst[e];
            acc0 = fmaf(hx[(size_t)t0 * 128 + f], bf2f(Wb[(size_t)e * 128 + f]), acc0);
        }
        agg[(size_t)a * 128 + f] = acc0 + acc1;
    }
}

// out[m] = sum_a ( ssp(h[m*32+a] @ out1_w + out1_b) @ out2_w + out2_b )
__global__ __launch_bounds__(64) void head_kernel(
    const float* __restrict__ h,
    const float* __restrict__ w1, const float* __restrict__ b1,
    const float* __restrict__ w2, const float* __restrict__ b2,
    float* __restrict__ out)
{
    const int m = blockIdx.x;
    const int f = threadIdx.x;   // 0..63
    float w1c[128];
    #pragma unroll
    for (int k = 0; k < 128; k++) w1c[k] = w1[k * 64 + f];
    const float b1f = b1[f];
    const float w2f = w2[f];
    __shared__ float sh[128];
    float acc = 0.0f;
    for (int a = 0; a < APM; a++) {
        const float* hr = h + (size_t)(m * APM + a) * 128;
        __syncthreads();
        sh[f]      = hr[f];
        sh[f + 64] = hr[f + 64];
        __syncthreads();
        float t = b1f;
        #pragma unroll
        for (int k = 0; k < 128; k += 4) {
            float4 xv = *(const float4*)&sh[k];
            t = fmaf(xv.x, w1c[k],     t);
            t = fmaf(xv.y, w1c[k + 1], t);
            t = fmaf(xv.z, w1c[k + 2], t);
            t = fmaf(xv.w, w1c[k + 3], t);
        }
        acc += ssp(t) * w2f;
    }
    #pragma unroll
    for (int off = 32; off > 0; off >>= 1) acc += __shfl_down(acc, off);
    if (f == 0) out[m] = acc + (float)APM * b2[0];
}

extern "C" void kernel_launch(void* const* d_in, const int* in_sizes, int n_in,
                              void* d_out, int out_size, void* d_ws, size_t ws_size,
                              hipStream_t stream)
{
    const int*   z      = (const int*)d_in[0];
    const float* pos    = (const float*)d_in[1];
    const int*   eidx   = (const int*)d_in[3];
    const float* emb    = (const float*)d_in[4];
    const float* mlp_w1 = (const float*)d_in[5];
    const float* mlp_b1 = (const float*)d_in[6];
    const float* mlp_w2 = (const float*)d_in[7];
    const float* mlp_b2 = (const float*)d_in[8];
    const float* cf1_w  = (const float*)d_in[9];
    const float* cf2_w  = (const float*)d_in[10];
    const float* cf2_b  = (const float*)d_in[11];
    const float* lin_w  = (const float*)d_in[12];
    const float* lin_b  = (const float*)d_in[13];
    const float* out1_w = (const float*)d_in[14];
    const float* out1_b = (const float*)d_in[15];
    const float* out2_w = (const float*)d_in[16];
    const float* out2_b = (const float*)d_in[17];
    const int E = in_sizes[3] / 2;
    const int ntiles = (E + 63) / 64;

    float* h   = (float*)d_ws;                        // [N,128]
    float* hx  = h   + (size_t)NATOMS * 128;          // [N,128]
    float* agg = hx  + (size_t)NATOMS * 128;          // [N,128]
    unsigned short* Wb = (unsigned short*)(agg + (size_t)NATOMS * 128);  // [E,128] bf16
    int* rowptr = (int*)(Wb + (size_t)E * 128);       // [NATOMS+1]
    unsigned short* Wtall = (unsigned short*)(rowptr + NATOMS + 2);      // [9][128][128] bf16

    embed_kernel<<<(NATOMS * 128) / 256, 256, 0, stream>>>(z, emb, h);
    rowptr_kernel<<<(NATOMS + 256) / 256, 256, 0, stream>>>(eidx, E, rowptr);
    prep_weights_kernel<<<(9 * 16384 + 255) / 256, 256, 0, stream>>>(
        cf1_w, cf2_w, lin_w, Wtall);

    const int wgrid = ntiles < 512 ? ntiles : 512;
    for (int l = 0; l < 3; l++) {
        gemm_mfma<0><<<NATOMS / 64, 256, 0, stream>>>(
            h, Wtall + (size_t)(l * 3 + 0) * 16384, nullptr, hx);
        edge_w_kernel<<<wgrid, 256, 0, stream>>>(
            pos, eidx, E, ntiles,
            mlp_w1 + (size_t)l * GDIM * 128, mlp_b1 + (size_t)l * 128,
            mlp_w2 + (size_t)l * 128 * 128,  mlp_b2 + (size_t)l * 128,
            Wb);
        gather_kernel<<<NATOMS / 16, 256, 0, stream>>>(eidx + E, rowptr, Wb, hx, agg);
        gemm_mfma<1><<<NATOMS / 64, 256, 0, stream>>>(
            agg, Wtall + (size_t)(l * 3 + 1) * 16384, cf2_b + (size_t)l * 128, hx);
        gemm_mfma<2><<<NATOMS / 64, 256, 0, stream>>>(
            hx, Wtall + (size_t)(l * 3 + 2) * 16384, lin_b + (size_t)l * 128, h);
    }

    head_kernel<<<NMOL, 64, 0, stream>>>(h, out1_w, out1_b, out2_w, out2_b,
                                         (float*)d_out);
}

// Round 5
// 323.054 us; speedup vs baseline: 7.8245x; 1.5216x over previous
//
#include <hip/hip_runtime.h>
#include <hip/hip_bf16.h>
#include <math.h>

// Problem constants (SchNet reference)
#define NATOMS 16384
#define NMOL   512
#define APM    32
#define GDIM   50
#define KTAB   2048   // filter lookup-table knots over d in [0,6]

typedef __attribute__((ext_vector_type(8))) short   short8;   // 8 bf16 (A/B frag)
typedef __attribute__((ext_vector_type(4))) float   floatx4;  // C/D frag

// fast shifted softplus: log(1+exp(x)) - log2, via HW v_exp_f32/v_log_f32
__device__ __forceinline__ float ssp(float x) {
    float e = __expf(-fabsf(x));
    return fmaxf(x, 0.0f) + __logf(1.0f + e) - 0.69314718055994531f;
}

__device__ __forceinline__ unsigned short f2bf(float x) {
    union { float f; unsigned int u; } v; v.f = x;
    unsigned int lsb = (v.u >> 16) & 1u;
    v.u += 0x7fffu + lsb;
    return (unsigned short)(v.u >> 16);
}

__device__ __forceinline__ unsigned int pk2bf(float a, float b) {
    __hip_bfloat162 h = __float22bfloat162_rn(make_float2(a, b));
    unsigned int u;
    __builtin_memcpy(&u, &h, 4);
    return u;
}

__device__ __forceinline__ float bf2f(unsigned int u16bits) {
    union { unsigned int u; float f; } v; v.u = u16bits << 16;
    return v.f;
}

// h[i][f] = emb[z[i]][f]
__global__ __launch_bounds__(256) void embed_kernel(
    const int* __restrict__ z, const float* __restrict__ emb,
    float* __restrict__ h)
{
    int idx = blockIdx.x * 256 + threadIdx.x;
    h[idx] = emb[(size_t)z[idx >> 7] * 128 + (idx & 127)];
}

// rowptr[a] = lower_bound(src, a)  (src globally sorted)
__global__ __launch_bounds__(256) void rowptr_kernel(
    const int* __restrict__ src, int E, int* __restrict__ rowptr)
{
    int a = blockIdx.x * 256 + threadIdx.x;
    if (a > NATOMS) return;
    int lo = 0, hi = E;
    while (lo < hi) { int mid = (lo + hi) >> 1; if (src[mid] < a) lo = mid + 1; else hi = mid; }
    rowptr[a] = lo;
}

// Pre-convert node-GEMM weights [k][n] fp32 -> [n][k] bf16 (B-frag layout)
__global__ __launch_bounds__(256) void prep_weights_kernel(
    const float* __restrict__ cf1, const float* __restrict__ cf2,
    const float* __restrict__ lin, unsigned short* __restrict__ Wtall)
{
    int idx = blockIdx.x * 256 + threadIdx.x;     // over 9*128*128
    if (idx >= 9 * 16384) return;
    int wi = idx >> 14, rem = idx & 16383;
    int n = rem >> 7, k = rem & 127;
    int l = wi / 3, which = wi % 3;
    const float* src = (which == 0) ? cf1 : (which == 1) ? cf2 : lin;
    Wtall[idx] = f2bf(src[(size_t)l * 16384 + k * 128 + n]);
}

// per-edge (i, frac) for table interpolation; d is layer-invariant
__global__ __launch_bounds__(256) void edge_ifr_kernel(
    const float* __restrict__ pos, const int* __restrict__ eidx, int E,
    uint2* __restrict__ ifr)
{
    int e = blockIdx.x * 256 + threadIdx.x;
    if (e >= E) return;
    int s = eidx[e], t = eidx[E + e];
    float dx = pos[3 * s]     - pos[3 * t];
    float dy = pos[3 * s + 1] - pos[3 * t + 1];
    float dz = pos[3 * s + 2] - pos[3 * t + 2];
    float d  = sqrtf(dx * dx + dy * dy + dz * dz);
    float u  = d * (float)(KTAB - 1) / 6.0f;
    int i = (int)u;
    i = min(i, KTAB - 2);
    float frac = u - (float)i;
    ifr[e] = make_uint2((unsigned)i, __float_as_uint(frac));
}

// ---------------------------------------------------------------------------
// Build filter table: T[l][k][f] = ((ssp(ea(d_k)@w1+b1)@w2)+b2)*cut(d_k), bf16
// One 64-knot tile per block (blockIdx.x), layer = blockIdx.y. MFMA pipeline
// identical to the old per-edge kernel, but only KTAB*3 rows total.
// ---------------------------------------------------------------------------
#define KW1 72    // s_w1T row stride in ushorts
#define KW2 136   // s_w2T / s_t row stride in ushorts

__global__ __launch_bounds__(256, 2) void build_table_kernel(
    const float* __restrict__ w1_, const float* __restrict__ b1_,
    const float* __restrict__ w2_, const float* __restrict__ b2_,
    unsigned short* __restrict__ T_)
{
    const int l = blockIdx.y;
    const float* w1 = w1_ + (size_t)l * GDIM * 128;
    const float* b1 = b1_ + (size_t)l * 128;
    const float* w2 = w2_ + (size_t)l * 128 * 128;
    const float* b2 = b2_ + (size_t)l * 128;
    unsigned short* T = T_ + (size_t)l * KTAB * 128;

    __shared__ unsigned short s_w1T[128 * KW1];
    __shared__ unsigned short s_w2T[128 * KW2];
    __shared__ unsigned short s_t[64 * KW2];

    const int tid = threadIdx.x;
    for (int i = tid; i < GDIM * 128; i += 256) {
        int g = i >> 7, f = i & 127;
        s_w1T[f * KW1 + g] = f2bf(w1[i]);
    }
    for (int i = tid; i < (64 - GDIM) * 128; i += 256) {
        int g = GDIM + (i >> 7), f = i & 127;
        s_w1T[f * KW1 + g] = 0;
    }
    for (int i = tid; i < 128 * 128; i += 256) {
        int k = i >> 7, n = i & 127;
        s_w2T[n * KW2 + k] = f2bf(w2[i]);
    }

    const int lane = tid & 63;
    const int w    = tid >> 6;
    const int l15  = lane & 15;
    const int quad = lane >> 4;

    float b1v[8], b2v[8];
    #pragma unroll
    for (int nt = 0; nt < 8; nt++) {
        b1v[nt] = b1[nt * 16 + l15];
        b2v[nt] = b2[nt * 16 + l15];
    }
    __syncthreads();

    const float hstep = 6.0f / (float)(KTAB - 1);
    const float step  = 6.0f / 49.0f;
    const float coeff = -0.5f / (step * step);
    const float pioc  = 3.14159265358979323846f / 6.0f;
    const int k0 = blockIdx.x * 64;
    const float dm = (float)(k0 + w * 16 + l15) * hstep;   // A-frag row m

    // ---- MFMA1: t_pre = ea @ w1, K = 64 (padded), 2 K-steps ----
    floatx4 acc1[8];
    #pragma unroll
    for (int nt = 0; nt < 8; nt++) acc1[nt] = (floatx4){0.f, 0.f, 0.f, 0.f};
    #pragma unroll
    for (int ks = 0; ks < 2; ks++) {
        unsigned int ap[4];
        #pragma unroll
        for (int jj = 0; jj < 4; jj++) {
            int g0 = ks * 32 + quad * 8 + 2 * jj;
            float d0 = dm - (float)g0 * step;
            float d1 = dm - (float)(g0 + 1) * step;
            float v0 = (g0 < GDIM)     ? __expf(coeff * d0 * d0) : 0.0f;
            float v1 = (g0 + 1 < GDIM) ? __expf(coeff * d1 * d1) : 0.0f;
            ap[jj] = pk2bf(v0, v1);
        }
        short8 af;
        __builtin_memcpy(&af, ap, 16);
        #pragma unroll
        for (int nt = 0; nt < 8; nt++) {
            short8 bfg = *(const short8*)&s_w1T[(nt * 16 + l15) * KW1 + ks * 32 + quad * 8];
            acc1[nt] = __builtin_amdgcn_mfma_f32_16x16x32_bf16(af, bfg, acc1[nt], 0, 0, 0);
        }
    }
    #pragma unroll
    for (int nt = 0; nt < 8; nt++) {
        #pragma unroll
        for (int r = 0; r < 4; r++) {
            int row = w * 16 + quad * 4 + r;
            s_t[row * KW2 + nt * 16 + l15] = f2bf(ssp(acc1[nt][r] + b1v[nt]));
        }
    }
    // no barrier: wave reads only rows it wrote

    // ---- MFMA2: Wv = t @ w2, K = 128 ----
    floatx4 acc2[8];
    #pragma unroll
    for (int nt = 0; nt < 8; nt++) acc2[nt] = (floatx4){0.f, 0.f, 0.f, 0.f};
    #pragma unroll
    for (int ks = 0; ks < 4; ks++) {
        short8 af = *(const short8*)&s_t[(w * 16 + l15) * KW2 + ks * 32 + quad * 8];
        #pragma unroll
        for (int nt = 0; nt < 8; nt++) {
            short8 bfg = *(const short8*)&s_w2T[(nt * 16 + l15) * KW2 + ks * 32 + quad * 8];
            acc2[nt] = __builtin_amdgcn_mfma_f32_16x16x32_bf16(af, bfg, acc2[nt], 0, 0, 0);
        }
    }

    float cut_r[4];
    #pragma unroll
    for (int r = 0; r < 4; r++) {
        float d = (float)(k0 + w * 16 + quad * 4 + r) * hstep;
        cut_r[r] = 0.5f * (__cosf(d * pioc) + 1.0f);
    }
    #pragma unroll
    for (int nt = 0; nt < 8; nt++) {
        #pragma unroll
        for (int r = 0; r < 4; r++) {
            int row = w * 16 + quad * 4 + r;
            float v = (acc2[nt][r] + b2v[nt]) * cut_r[r];
            T[(size_t)(k0 + row) * 128 + nt * 16 + l15] = f2bf(v);
        }
    }
}

// pack neighbor knots: Tp[l][k][f] = (T[k][f] , T[k+1][f]) as bf16x2 in a uint
__global__ __launch_bounds__(256) void pack_table_kernel(
    const unsigned short* __restrict__ T, unsigned int* __restrict__ Tp)
{
    int idx = blockIdx.x * 256 + threadIdx.x;    // over 3*KTAB*128
    int k = (idx >> 7) & (KTAB - 1);
    unsigned int lo = T[idx];
    unsigned int hi = (k == KTAB - 1) ? lo : T[idx + 128];
    Tp[idx] = lo | (hi << 16);
}

// ---------------------------------------------------------------------------
// Node GEMM via MFMA bf16: Y[n][f] = X[n][:] @ W  (cf1, no bias)
// ---------------------------------------------------------------------------
__global__ __launch_bounds__(256, 2) void gemm_mfma(
    const float* __restrict__ X, const unsigned short* __restrict__ Wt,
    float* __restrict__ Y)
{
    __shared__ unsigned short s_x[64 * 136];
    const int tid  = threadIdx.x;
    const int lane = tid & 63;
    const int w    = tid >> 6;
    const int l15  = lane & 15;
    const int quad = lane >> 4;
    const int base = blockIdx.x * 64;

    #pragma unroll
    for (int it = 0; it < 4; it++) {
        int idx = it * 2048 + tid * 8;
        const float4 xa = *(const float4*)&X[(size_t)base * 128 + idx];
        const float4 xb = *(const float4*)&X[(size_t)base * 128 + idx + 4];
        int row = idx >> 7, col = idx & 127;
        unsigned int p[4];
        p[0] = pk2bf(xa.x, xa.y); p[1] = pk2bf(xa.z, xa.w);
        p[2] = pk2bf(xb.x, xb.y); p[3] = pk2bf(xb.z, xb.w);
        __builtin_memcpy(&s_x[row * 136 + col], p, 16);
    }
    __syncthreads();

    floatx4 acc[8];
    #pragma unroll
    for (int nt = 0; nt < 8; nt++) acc[nt] = (floatx4){0.f, 0.f, 0.f, 0.f};
    #pragma unroll
    for (int ks = 0; ks < 4; ks++) {
        short8 af = *(const short8*)&s_x[(w * 16 + l15) * 136 + ks * 32 + quad * 8];
        #pragma unroll
        for (int nt = 0; nt < 8; nt++) {
            short8 bfg = *(const short8*)&Wt[(size_t)(nt * 16 + l15) * 128 + ks * 32 + quad * 8];
            acc[nt] = __builtin_amdgcn_mfma_f32_16x16x32_bf16(af, bfg, acc[nt], 0, 0, 0);
        }
    }
    #pragma unroll
    for (int nt = 0; nt < 8; nt++) {
        #pragma unroll
        for (int r = 0; r < 4; r++) {
            int row = w * 16 + quad * 4 + r;
            Y[(size_t)(base + row) * 128 + nt * 16 + l15] = acc[nt][r];
        }
    }
}

// ---------------------------------------------------------------------------
// Fused cf2 + ssp + lin + residual:
//   v = ssp(X @ cf2 + ba);  H += v @ lin + bb
// Same C-layout -> LDS -> A-layout round trip as the table builder.
// ---------------------------------------------------------------------------
__global__ __launch_bounds__(256, 2) void cf2lin_kernel(
    const float* __restrict__ X,
    const unsigned short* __restrict__ Wa, const float* __restrict__ ba,
    const unsigned short* __restrict__ Wb, const float* __restrict__ bb,
    float* __restrict__ H)
{
    __shared__ unsigned short s_x[64 * 136];
    __shared__ unsigned short s_t[64 * 136];
    const int tid  = threadIdx.x;
    const int lane = tid & 63;
    const int w    = tid >> 6;
    const int l15  = lane & 15;
    const int quad = lane >> 4;
    const int base = blockIdx.x * 64;

    #pragma unroll
    for (int it = 0; it < 4; it++) {
        int idx = it * 2048 + tid * 8;
        const float4 xa = *(const float4*)&X[(size_t)base * 128 + idx];
        const float4 xb = *(const float4*)&X[(size_t)base * 128 + idx + 4];
        int row = idx >> 7, col = idx & 127;
        unsigned int p[4];
        p[0] = pk2bf(xa.x, xa.y); p[1] = pk2bf(xa.z, xa.w);
        p[2] = pk2bf(xb.x, xb.y); p[3] = pk2bf(xb.z, xb.w);
        __builtin_memcpy(&s_x[row * 136 + col], p, 16);
    }
    float bva[8], bvb[8];
    #pragma unroll
    for (int nt = 0; nt < 8; nt++) {
        bva[nt] = ba[nt * 16 + l15];
        bvb[nt] = bb[nt * 16 + l15];
    }
    __syncthreads();

    floatx4 acc1[8];
    #pragma unroll
    for (int nt = 0; nt < 8; nt++) acc1[nt] = (floatx4){0.f, 0.f, 0.f, 0.f};
    #pragma unroll
    for (int ks = 0; ks < 4; ks++) {
        short8 af = *(const short8*)&s_x[(w * 16 + l15) * 136 + ks * 32 + quad * 8];
        #pragma unroll
        for (int nt = 0; nt < 8; nt++) {
            short8 bfg = *(const short8*)&Wa[(size_t)(nt * 16 + l15) * 128 + ks * 32 + quad * 8];
            acc1[nt] = __builtin_amdgcn_mfma_f32_16x16x32_bf16(af, bfg, acc1[nt], 0, 0, 0);
        }
    }
    #pragma unroll
    for (int nt = 0; nt < 8; nt++) {
        #pragma unroll
        for (int r = 0; r < 4; r++) {
            int row = w * 16 + quad * 4 + r;
            s_t[row * 136 + nt * 16 + l15] = f2bf(ssp(acc1[nt][r] + bva[nt]));
        }
    }
    // no barrier: wave reads only rows it wrote

    floatx4 acc2[8];
    #pragma unroll
    for (int nt = 0; nt < 8; nt++) acc2[nt] = (floatx4){0.f, 0.f, 0.f, 0.f};
    #pragma unroll
    for (int ks = 0; ks < 4; ks++) {
        short8 af = *(const short8*)&s_t[(w * 16 + l15) * 136 + ks * 32 + quad * 8];
        #pragma unroll
        for (int nt = 0; nt < 8; nt++) {
            short8 bfg = *(const short8*)&Wb[(size_t)(nt * 16 + l15) * 128 + ks * 32 + quad * 8];
            acc2[nt] = __builtin_amdgcn_mfma_f32_16x16x32_bf16(af, bfg, acc2[nt], 0, 0, 0);
        }
    }
    #pragma unroll
    for (int nt = 0; nt < 8; nt++) {
        #pragma unroll
        for (int r = 0; r < 4; r++) {
            int row = w * 16 + quad * 4 + r;
            size_t o = (size_t)(base + row) * 128 + nt * 16 + l15;
            H[o] += acc2[nt][r] + bvb[nt];
        }
    }
}

// ---------------------------------------------------------------------------
// Fused symmetric gather + table lerp:
//   agg[a][f] = sum_{e in row a} hx[dst[e]][f] * lerp(Tp[i_e], frac_e)[f]
// Wave-uniform edge metadata (dst, ifr) -> scalar loads; 2 f per thread.
// ---------------------------------------------------------------------------
__global__ __launch_bounds__(256) void gather_fused_kernel(
    const int* __restrict__ dst, const int* __restrict__ rowptr,
    const uint2* __restrict__ ifr, const unsigned int* __restrict__ Tp,
    const float* __restrict__ hx, float* __restrict__ agg)
{
    const int tid = threadIdx.x;
    const int f2  = (tid & 63) * 2;
    const int sub = tid >> 6;           // wave id; whole wave shares an atom
    const int a0  = blockIdx.x * 16;

    for (int r = sub; r < 16; r += 4) {
        const int a  = a0 + r;
        const int e0 = rowptr[a];
        const int e1 = rowptr[a + 1];
        float accx0 = 0.f, accy0 = 0.f, accx1 = 0.f, accy1 = 0.f;
        int e = e0;
        for (; e + 1 < e1; e += 2) {
            int   t0 = dst[e],  t1 = dst[e + 1];
            uint2 q0 = ifr[e];
            uint2 q1 = ifr[e + 1];
            uint2 tpa = *(const uint2*)&Tp[(size_t)q0.x * 128 + f2];
            uint2 tpb = *(const uint2*)&Tp[(size_t)q1.x * 128 + f2];
            float2 ha = *(const float2*)&hx[(size_t)t0 * 128 + f2];
            float2 hb = *(const float2*)&hx[(size_t)t1 * 128 + f2];
            float fra = __uint_as_float(q0.y);
            float frb = __uint_as_float(q1.y);
            float w0, w1;
            w0 = bf2f(tpa.x & 0xffffu); w1 = bf2f(tpa.x >> 16);
            accx0 = fmaf(ha.x, fmaf(fra, w1 - w0, w0), accx0);
            w0 = bf2f(tpa.y & 0xffffu); w1 = bf2f(tpa.y >> 16);
            accy0 = fmaf(ha.y, fmaf(fra, w1 - w0, w0), accy0);
            w0 = bf2f(tpb.x & 0xffffu); w1 = bf2f(tpb.x >> 16);
            accx1 = fmaf(hb.x, fmaf(frb, w1 - w0, w0), accx1);
            w0 = bf2f(tpb.y & 0xffffu); w1 = bf2f(tpb.y >> 16);
            accy1 = fmaf(hb.y, fmaf(frb, w1 - w0, w0), accy1);
        }
        if (e < e1) {
            int   t0 = dst[e];
            uint2 q0 = ifr[e];
            uint2 tpa = *(const uint2*)&Tp[(size_t)q0.x * 128 + f2];
            float2 ha = *(const float2*)&hx[(size_t)t0 * 128 + f2];
            float fra = __uint_as_float(q0.y);
            float w0, w1;
            w0 = bf2f(tpa.x & 0xffffu); w1 = bf2f(tpa.x >> 16);
            accx0 = fmaf(ha.x, fmaf(fra, w1 - w0, w0), accx0);
            w0 = bf2f(tpa.y & 0xffffu); w1 = bf2f(tpa.y >> 16);
            accy0 = fmaf(ha.y, fmaf(fra, w1 - w0, w0), accy0);
        }
        float2 out = make_float2(accx0 + accx1, accy0 + accy1);
        *(float2*)&agg[(size_t)a * 128 + f2] = out;
    }
}

// out[m] = sum_a ( ssp(h[m*32+a] @ out1_w + out1_b) @ out2_w + out2_b )
__global__ __launch_bounds__(64) void head_kernel(
    const float* __restrict__ h,
    const float* __restrict__ w1, const float* __restrict__ b1,
    const float* __restrict__ w2, const float* __restrict__ b2,
    float* __restrict__ out)
{
    const int m = blockIdx.x;
    const int f = threadIdx.x;   // 0..63
    float w1c[128];
    #pragma unroll
    for (int k = 0; k < 128; k++) w1c[k] = w1[k * 64 + f];
    const float b1f = b1[f];
    const float w2f = w2[f];
    __shared__ float sh[128];
    float acc = 0.0f;
    for (int a = 0; a < APM; a++) {
        const float* hr = h + (size_t)(m * APM + a) * 128;
        __syncthreads();
        sh[f]      = hr[f];
        sh[f + 64] = hr[f + 64];
        __syncthreads();
        float t = b1f;
        #pragma unroll
        for (int k = 0; k < 128; k += 4) {
            float4 xv = *(const float4*)&sh[k];
            t = fmaf(xv.x, w1c[k],     t);
            t = fmaf(xv.y, w1c[k + 1], t);
            t = fmaf(xv.z, w1c[k + 2], t);
            t = fmaf(xv.w, w1c[k + 3], t);
        }
        acc += ssp(t) * w2f;
    }
    #pragma unroll
    for (int off = 32; off > 0; off >>= 1) acc += __shfl_down(acc, off);
    if (f == 0) out[m] = acc + (float)APM * b2[0];
}

extern "C" void kernel_launch(void* const* d_in, const int* in_sizes, int n_in,
                              void* d_out, int out_size, void* d_ws, size_t ws_size,
                              hipStream_t stream)
{
    const int*   z      = (const int*)d_in[0];
    const float* pos    = (const float*)d_in[1];
    const int*   eidx   = (const int*)d_in[3];
    const float* emb    = (const float*)d_in[4];
    const float* mlp_w1 = (const float*)d_in[5];
    const float* mlp_b1 = (const float*)d_in[6];
    const float* mlp_w2 = (const float*)d_in[7];
    const float* mlp_b2 = (const float*)d_in[8];
    const float* cf1_w  = (const float*)d_in[9];
    const float* cf2_w  = (const float*)d_in[10];
    const float* cf2_b  = (const float*)d_in[11];
    const float* lin_w  = (const float*)d_in[12];
    const float* lin_b  = (const float*)d_in[13];
    const float* out1_w = (const float*)d_in[14];
    const float* out1_b = (const float*)d_in[15];
    const float* out2_w = (const float*)d_in[16];
    const float* out2_b = (const float*)d_in[17];
    const int E = in_sizes[3] / 2;

    float* h   = (float*)d_ws;                        // [N,128]
    float* hx  = h   + (size_t)NATOMS * 128;
    float* agg = hx  + (size_t)NATOMS * 128;
    uint2* ifr = (uint2*)(agg + (size_t)NATOMS * 128);             // [E]
    unsigned int* Tp = (unsigned int*)(ifr + E);                   // [3][KTAB][128]
    int* rowptr = (int*)(Tp + (size_t)3 * KTAB * 128);             // [N+1]
    unsigned short* Ttab = (unsigned short*)(rowptr + NATOMS + 2); // [3][KTAB][128]
    unsigned short* Wtall = Ttab + (size_t)3 * KTAB * 128;         // [9][128][128]

    embed_kernel<<<(NATOMS * 128) / 256, 256, 0, stream>>>(z, emb, h);
    rowptr_kernel<<<(NATOMS + 256) / 256, 256, 0, stream>>>(eidx, E, rowptr);
    prep_weights_kernel<<<(9 * 16384 + 255) / 256, 256, 0, stream>>>(
        cf1_w, cf2_w, lin_w, Wtall);
    build_table_kernel<<<dim3(KTAB / 64, 3), 256, 0, stream>>>(
        mlp_w1, mlp_b1, mlp_w2, mlp_b2, Ttab);
    pack_table_kernel<<<3 * KTAB * 128 / 256, 256, 0, stream>>>(Ttab, Tp);
    edge_ifr_kernel<<<(E + 255) / 256, 256, 0, stream>>>(pos, eidx, E, ifr);

    for (int l = 0; l < 3; l++) {
        gemm_mfma<<<NATOMS / 64, 256, 0, stream>>>(
            h, Wtall + (size_t)(l * 3 + 0) * 16384, hx);
        gather_fused_kernel<<<NATOMS / 16, 256, 0, stream>>>(
            eidx + E, rowptr, ifr, Tp + (size_t)l * KTAB * 128, hx, agg);
        cf2lin_kernel<<<NATOMS / 64, 256, 0, stream>>>(
            agg,
            Wtall + (size_t)(l * 3 + 1) * 16384, cf2_b + (size_t)l * 128,
            Wtall + (size_t)(l * 3 + 2) * 16384, lin_b + (size_t)l * 128,
            h);
    }

    head_kernel<<<NMOL, 64, 0, stream>>>(h, out1_w, out1_b, out2_w, out2_b,
                                         (float*)d_out);
}

// Round 6
// 268.492 us; speedup vs baseline: 9.4146x; 1.2032x over previous
//
#include <hip/hip_runtime.h>
#include <hip/hip_bf16.h>
#include <math.h>

// Problem constants (SchNet reference)
#define NATOMS 16384
#define NMOL   512
#define APM    32
#define GDIM   50
#define KTAB   2048   // filter lookup-table knots over d in [0,6]

#define STRH 132      // s_h row stride (floats), 528B = 16B-aligned, +4 pad
#define STRA 136      // s_agg / s_t row stride (ushorts), 272B = 16B-aligned

typedef __attribute__((ext_vector_type(8))) short   short8;   // 8 bf16 (A/B frag)
typedef __attribute__((ext_vector_type(4))) float   floatx4;  // C/D frag

// fast shifted softplus: log(1+exp(x)) - log2, via HW v_exp_f32/v_log_f32
__device__ __forceinline__ float ssp(float x) {
    float e = __expf(-fabsf(x));
    return fmaxf(x, 0.0f) + __logf(1.0f + e) - 0.69314718055994531f;
}

__device__ __forceinline__ unsigned short f2bf(float x) {
    union { float f; unsigned int u; } v; v.f = x;
    unsigned int lsb = (v.u >> 16) & 1u;
    v.u += 0x7fffu + lsb;
    return (unsigned short)(v.u >> 16);
}

__device__ __forceinline__ unsigned int pk2bf(float a, float b) {
    __hip_bfloat162 h = __float22bfloat162_rn(make_float2(a, b));
    unsigned int u;
    __builtin_memcpy(&u, &h, 4);
    return u;
}

__device__ __forceinline__ float bf2f(unsigned int u16bits) {
    union { unsigned int u; float f; } v; v.u = u16bits << 16;
    return v.f;
}

// rowptr[a] = lower_bound(src, a)  (src globally sorted)
__global__ __launch_bounds__(256) void rowptr_kernel(
    const int* __restrict__ src, int E, int* __restrict__ rowptr)
{
    int a = blockIdx.x * 256 + threadIdx.x;
    if (a > NATOMS) return;
    int lo = 0, hi = E;
    while (lo < hi) { int mid = (lo + hi) >> 1; if (src[mid] < a) lo = mid + 1; else hi = mid; }
    rowptr[a] = lo;
}

// Pre-convert node-GEMM weights [k][n] fp32 -> [n][k] bf16 (B-frag layout).
// Layout: 9 * 128x128 (cf1/cf2/lin per layer), then out1_w^T 64x128.
__global__ __launch_bounds__(256) void prep_weights_kernel(
    const float* __restrict__ cf1, const float* __restrict__ cf2,
    const float* __restrict__ lin, const float* __restrict__ out1,
    unsigned short* __restrict__ Wtall)
{
    int idx = blockIdx.x * 256 + threadIdx.x;
    if (idx < 9 * 16384) {
        int wi = idx >> 14, rem = idx & 16383;
        int n = rem >> 7, k = rem & 127;
        int l = wi / 3, which = wi % 3;
        const float* src = (which == 0) ? cf1 : (which == 1) ? cf2 : lin;
        Wtall[idx] = f2bf(src[(size_t)l * 16384 + k * 128 + n]);
    } else if (idx < 9 * 16384 + 64 * 128) {
        int r = idx - 9 * 16384;
        int n = r >> 7, k = r & 127;
        Wtall[idx] = f2bf(out1[k * 64 + n]);
    }
}

// per-edge (i, frac) for table interpolation; d is layer-invariant
__global__ __launch_bounds__(256) void edge_ifr_kernel(
    const float* __restrict__ pos, const int* __restrict__ eidx, int E,
    uint2* __restrict__ ifr)
{
    int e = blockIdx.x * 256 + threadIdx.x;
    if (e >= E) return;
    int s = eidx[e], t = eidx[E + e];
    float dx = pos[3 * s]     - pos[3 * t];
    float dy = pos[3 * s + 1] - pos[3 * t + 1];
    float dz = pos[3 * s + 2] - pos[3 * t + 2];
    float d  = sqrtf(dx * dx + dy * dy + dz * dz);
    float u  = d * (float)(KTAB - 1) / 6.0f;
    int i = (int)u;
    i = min(i, KTAB - 2);
    float frac = u - (float)i;
    ifr[e] = make_uint2((unsigned)i, __float_as_uint(frac));
}

// ---------------------------------------------------------------------------
// Build filter table: T[l][k][f] = ((ssp(ea(d_k)@w1+b1)@w2)+b2)*cut(d_k), bf16
// ---------------------------------------------------------------------------
#define KW1 72
#define KW2 136

__global__ __launch_bounds__(256, 2) void build_table_kernel(
    const float* __restrict__ w1_, const float* __restrict__ b1_,
    const float* __restrict__ w2_, const float* __restrict__ b2_,
    unsigned short* __restrict__ T_)
{
    const int l = blockIdx.y;
    const float* w1 = w1_ + (size_t)l * GDIM * 128;
    const float* b1 = b1_ + (size_t)l * 128;
    const float* w2 = w2_ + (size_t)l * 128 * 128;
    const float* b2 = b2_ + (size_t)l * 128;
    unsigned short* T = T_ + (size_t)l * KTAB * 128;

    __shared__ unsigned short s_w1T[128 * KW1];
    __shared__ unsigned short s_w2T[128 * KW2];
    __shared__ unsigned short s_t[64 * KW2];

    const int tid = threadIdx.x;
    for (int i = tid; i < GDIM * 128; i += 256) {
        int g = i >> 7, f = i & 127;
        s_w1T[f * KW1 + g] = f2bf(w1[i]);
    }
    for (int i = tid; i < (64 - GDIM) * 128; i += 256) {
        int g = GDIM + (i >> 7), f = i & 127;
        s_w1T[f * KW1 + g] = 0;
    }
    for (int i = tid; i < 128 * 128; i += 256) {
        int k = i >> 7, n = i & 127;
        s_w2T[n * KW2 + k] = f2bf(w2[i]);
    }

    const int lane = tid & 63;
    const int w    = tid >> 6;
    const int l15  = lane & 15;
    const int quad = lane >> 4;

    float b1v[8], b2v[8];
    #pragma unroll
    for (int nt = 0; nt < 8; nt++) {
        b1v[nt] = b1[nt * 16 + l15];
        b2v[nt] = b2[nt * 16 + l15];
    }
    __syncthreads();

    const float hstep = 6.0f / (float)(KTAB - 1);
    const float step  = 6.0f / 49.0f;
    const float coeff = -0.5f / (step * step);
    const float pioc  = 3.14159265358979323846f / 6.0f;
    const int k0 = blockIdx.x * 64;
    const float dm = (float)(k0 + w * 16 + l15) * hstep;

    floatx4 acc1[8];
    #pragma unroll
    for (int nt = 0; nt < 8; nt++) acc1[nt] = (floatx4){0.f, 0.f, 0.f, 0.f};
    #pragma unroll
    for (int ks = 0; ks < 2; ks++) {
        unsigned int ap[4];
        #pragma unroll
        for (int jj = 0; jj < 4; jj++) {
            int g0 = ks * 32 + quad * 8 + 2 * jj;
            float d0 = dm - (float)g0 * step;
            float d1 = dm - (float)(g0 + 1) * step;
            float v0 = (g0 < GDIM)     ? __expf(coeff * d0 * d0) : 0.0f;
            float v1 = (g0 + 1 < GDIM) ? __expf(coeff * d1 * d1) : 0.0f;
            ap[jj] = pk2bf(v0, v1);
        }
        short8 af;
        __builtin_memcpy(&af, ap, 16);
        #pragma unroll
        for (int nt = 0; nt < 8; nt++) {
            short8 bfg = *(const short8*)&s_w1T[(nt * 16 + l15) * KW1 + ks * 32 + quad * 8];
            acc1[nt] = __builtin_amdgcn_mfma_f32_16x16x32_bf16(af, bfg, acc1[nt], 0, 0, 0);
        }
    }
    #pragma unroll
    for (int nt = 0; nt < 8; nt++) {
        #pragma unroll
        for (int r = 0; r < 4; r++) {
            int row = w * 16 + quad * 4 + r;
            s_t[row * KW2 + nt * 16 + l15] = f2bf(ssp(acc1[nt][r] + b1v[nt]));
        }
    }
    // no barrier: wave reads only rows it wrote

    floatx4 acc2[8];
    #pragma unroll
    for (int nt = 0; nt < 8; nt++) acc2[nt] = (floatx4){0.f, 0.f, 0.f, 0.f};
    #pragma unroll
    for (int ks = 0; ks < 4; ks++) {
        short8 af = *(const short8*)&s_t[(w * 16 + l15) * KW2 + ks * 32 + quad * 8];
        #pragma unroll
        for (int nt = 0; nt < 8; nt++) {
            short8 bfg = *(const short8*)&s_w2T[(nt * 16 + l15) * KW2 + ks * 32 + quad * 8];
            acc2[nt] = __builtin_amdgcn_mfma_f32_16x16x32_bf16(af, bfg, acc2[nt], 0, 0, 0);
        }
    }

    #pragma unroll
    for (int nt = 0; nt < 8; nt++) {
        #pragma unroll
        for (int r = 0; r < 4; r++) {
            int row = w * 16 + quad * 4 + r;
            float d = (float)(k0 + row) * hstep;
            float cut = 0.5f * (__cosf(d * pioc) + 1.0f);
            T[(size_t)(k0 + row) * 128 + nt * 16 + l15] = f2bf((acc2[nt][r] + b2v[nt]) * cut);
        }
    }
}

// pack neighbor knots: Tp[l][k][f] = (T[k][f] , T[k+1][f]) as bf16x2 in a uint
__global__ __launch_bounds__(256) void pack_table_kernel(
    const unsigned short* __restrict__ T, unsigned int* __restrict__ Tp)
{
    int idx = blockIdx.x * 256 + threadIdx.x;    // over 3*KTAB*128
    int k = (idx >> 7) & (KTAB - 1);
    unsigned int lo = T[idx];
    unsigned int hi = (k == KTAB - 1) ? lo : T[idx + 128];
    Tp[idx] = lo | (hi << 16);
}

// ---------------------------------------------------------------------------
// Fully-fused SchNet: one block = one molecule (32 atoms), 128 threads.
// h / hx / agg / t live in LDS for the whole network. Weights (bf16 B-frag)
// and lerp table stream from L2. Zero intermediate HBM traffic.
// ---------------------------------------------------------------------------
__global__ __launch_bounds__(128) void fused_schnet_kernel(
    const int* __restrict__ z, const float* __restrict__ emb,
    const int* __restrict__ dst, const int* __restrict__ rowptr,
    const uint2* __restrict__ ifr, const unsigned int* __restrict__ Tp,
    const unsigned short* __restrict__ Wtall,
    const float* __restrict__ cf2_b, const float* __restrict__ lin_b,
    const float* __restrict__ out1_b, const float* __restrict__ out2_w,
    const float* __restrict__ out2_b,
    float* __restrict__ out)
{
    __shared__ float s_h[32 * STRH];                 // 16.9 KB, fp32 node state
    __shared__ float s_hx[32 * 128];                 // 16.4 KB (aliased by s_t)
    __shared__ unsigned short s_agg[32 * STRA];      //  8.7 KB
    __shared__ float s_red;
    unsigned short* s_t = (unsigned short*)s_hx;     // [32][STRA] bf16 alias

    const int tid  = threadIdx.x;
    const int lane = tid & 63;
    const int w    = tid >> 6;          // wave 0..1; owns rows [w*16, w*16+16)
    const int l15  = lane & 15;
    const int quad = lane >> 4;
    const int B0   = blockIdx.x * 32;   // molecule base atom

    // init h from embedding (row uniform per iteration -> scalar z load)
    for (int i = tid; i < 32 * 128; i += 128) {
        int row = i >> 7, col = i & 127;
        s_h[row * STRH + col] = emb[(size_t)z[B0 + row] * 128 + col];
    }
    if (tid == 0) s_red = 0.0f;

    // prefetch row pointers for this wave's 16 atoms (17 bounds in lanes 0..16)
    const int rp = rowptr[B0 + w * 16 + min(lane, 16)];

    const unsigned short* WtO = Wtall + 9 * 16384;   // out1^T

    for (int l = 0; l < 3; l++) {
        const unsigned short* W1 = Wtall + (size_t)(l * 3 + 0) * 16384;
        const unsigned short* W2 = Wtall + (size_t)(l * 3 + 1) * 16384;
        const unsigned short* W3 = Wtall + (size_t)(l * 3 + 2) * 16384;
        const unsigned int* Tpl  = Tp + (size_t)l * KTAB * 128;

        __syncthreads();   // layer top: h ready; prev-layer s_t reads done

        // ---- GEMM1: hx = h @ cf1 (fp32 A from LDS, cvt to bf16 frags) ----
        floatx4 acc[8];
        #pragma unroll
        for (int nt = 0; nt < 8; nt++) acc[nt] = (floatx4){0.f, 0.f, 0.f, 0.f};
        #pragma unroll
        for (int ks = 0; ks < 4; ks++) {
            const float* hp = &s_h[(w * 16 + l15) * STRH + ks * 32 + quad * 8];
            float4 xa = *(const float4*)hp;
            float4 xb = *(const float4*)(hp + 4);
            unsigned int ap[4];
            ap[0] = pk2bf(xa.x, xa.y); ap[1] = pk2bf(xa.z, xa.w);
            ap[2] = pk2bf(xb.x, xb.y); ap[3] = pk2bf(xb.z, xb.w);
            short8 af;
            __builtin_memcpy(&af, ap, 16);
            #pragma unroll
            for (int nt = 0; nt < 8; nt++) {
                short8 bfg = *(const short8*)&W1[(size_t)(nt * 16 + l15) * 128 + ks * 32 + quad * 8];
                acc[nt] = __builtin_amdgcn_mfma_f32_16x16x32_bf16(af, bfg, acc[nt], 0, 0, 0);
            }
        }
        #pragma unroll
        for (int nt = 0; nt < 8; nt++) {
            #pragma unroll
            for (int r = 0; r < 4; r++)
                s_hx[(w * 16 + quad * 4 + r) * 128 + nt * 16 + l15] = acc[nt][r];
        }

        __syncthreads();   // hx complete before cross-row gather reads

        // ---- gather + lerp: agg[a] = sum_e hx[nbr]*lerp(Tp) (wave per atom) ----
        for (int al = 0; al < 16; al++) {
            const int e0 = __shfl(rp, al);
            const int e1 = __shfl(rp, al + 1);
            float ax[4] = {0.f, 0.f, 0.f, 0.f};
            float ay[4] = {0.f, 0.f, 0.f, 0.f};
            int e = e0;
            for (; e + 3 < e1; e += 4) {
                #pragma unroll
                for (int j = 0; j < 4; j++) {
                    int tl = dst[e + j] - B0;
                    uint2 q = ifr[e + j];
                    uint2 tp = *(const uint2*)&Tpl[(size_t)q.x * 128 + 2 * lane];
                    float2 hv = *(const float2*)&s_hx[tl * 128 + 2 * lane];
                    float fr = __uint_as_float(q.y);
                    float w0 = bf2f(tp.x & 0xffffu), w1 = bf2f(tp.x >> 16);
                    ax[j] = fmaf(hv.x, fmaf(fr, w1 - w0, w0), ax[j]);
                    w0 = bf2f(tp.y & 0xffffu); w1 = bf2f(tp.y >> 16);
                    ay[j] = fmaf(hv.y, fmaf(fr, w1 - w0, w0), ay[j]);
                }
            }
            for (; e < e1; e++) {
                int tl = dst[e] - B0;
                uint2 q = ifr[e];
                uint2 tp = *(const uint2*)&Tpl[(size_t)q.x * 128 + 2 * lane];
                float2 hv = *(const float2*)&s_hx[tl * 128 + 2 * lane];
                float fr = __uint_as_float(q.y);
                float w0 = bf2f(tp.x & 0xffffu), w1 = bf2f(tp.x >> 16);
                ax[0] = fmaf(hv.x, fmaf(fr, w1 - w0, w0), ax[0]);
                w0 = bf2f(tp.y & 0xffffu); w1 = bf2f(tp.y >> 16);
                ay[0] = fmaf(hv.y, fmaf(fr, w1 - w0, w0), ay[0]);
            }
            float sx = (ax[0] + ax[1]) + (ax[2] + ax[3]);
            float sy = (ay[0] + ay[1]) + (ay[2] + ay[3]);
            *(unsigned int*)&s_agg[(w * 16 + al) * STRA + 2 * lane] = pk2bf(sx, sy);
        }

        __syncthreads();   // all s_hx reads done before s_t (alias) writes

        // ---- GEMM2: t = ssp(agg @ cf2 + b) ----
        float bva[8], bvb[8];
        #pragma unroll
        for (int nt = 0; nt < 8; nt++) {
            bva[nt] = cf2_b[l * 128 + nt * 16 + l15];
            bvb[nt] = lin_b[l * 128 + nt * 16 + l15];
        }
        #pragma unroll
        for (int nt = 0; nt < 8; nt++) acc[nt] = (floatx4){0.f, 0.f, 0.f, 0.f};
        #pragma unroll
        for (int ks = 0; ks < 4; ks++) {
            short8 af = *(const short8*)&s_agg[(w * 16 + l15) * STRA + ks * 32 + quad * 8];
            #pragma unroll
            for (int nt = 0; nt < 8; nt++) {
                short8 bfg = *(const short8*)&W2[(size_t)(nt * 16 + l15) * 128 + ks * 32 + quad * 8];
                acc[nt] = __builtin_amdgcn_mfma_f32_16x16x32_bf16(af, bfg, acc[nt], 0, 0, 0);
            }
        }
        #pragma unroll
        for (int nt = 0; nt < 8; nt++) {
            #pragma unroll
            for (int r = 0; r < 4; r++) {
                int row = w * 16 + quad * 4 + r;
                s_t[row * STRA + nt * 16 + l15] = f2bf(ssp(acc[nt][r] + bva[nt]));
            }
        }
        // no barrier: wave reads only s_t rows it wrote

        // ---- GEMM3: h += t @ lin + b ----
        #pragma unroll
        for (int nt = 0; nt < 8; nt++) acc[nt] = (floatx4){0.f, 0.f, 0.f, 0.f};
        #pragma unroll
        for (int ks = 0; ks < 4; ks++) {
            short8 af = *(const short8*)&s_t[(w * 16 + l15) * STRA + ks * 32 + quad * 8];
            #pragma unroll
            for (int nt = 0; nt < 8; nt++) {
                short8 bfg = *(const short8*)&W3[(size_t)(nt * 16 + l15) * 128 + ks * 32 + quad * 8];
                acc[nt] = __builtin_amdgcn_mfma_f32_16x16x32_bf16(af, bfg, acc[nt], 0, 0, 0);
            }
        }
        #pragma unroll
        for (int nt = 0; nt < 8; nt++) {
            #pragma unroll
            for (int r = 0; r < 4; r++) {
                int row = w * 16 + quad * 4 + r;
                s_h[row * STRH + nt * 16 + l15] += acc[nt][r] + bvb[nt];
            }
        }
    }

    __syncthreads();

    // ---- head: out = sum_a ssp(h@out1 + b1)@out2 + 32*b2 ----
    floatx4 ha[4];
    #pragma unroll
    for (int nt = 0; nt < 4; nt++) ha[nt] = (floatx4){0.f, 0.f, 0.f, 0.f};
    #pragma unroll
    for (int ks = 0; ks < 4; ks++) {
        const float* hp = &s_h[(w * 16 + l15) * STRH + ks * 32 + quad * 8];
        float4 xa = *(const float4*)hp;
        float4 xb = *(const float4*)(hp + 4);
        unsigned int ap[4];
        ap[0] = pk2bf(xa.x, xa.y); ap[1] = pk2bf(xa.z, xa.w);
        ap[2] = pk2bf(xb.x, xb.y); ap[3] = pk2bf(xb.z, xb.w);
        short8 af;
        __builtin_memcpy(&af, ap, 16);
        #pragma unroll
        for (int nt = 0; nt < 4; nt++) {
            short8 bfg = *(const short8*)&WtO[(size_t)(nt * 16 + l15) * 128 + ks * 32 + quad * 8];
            ha[nt] = __builtin_amdgcn_mfma_f32_16x16x32_bf16(af, bfg, ha[nt], 0, 0, 0);
        }
    }
    float part = 0.0f;
    #pragma unroll
    for (int nt = 0; nt < 4; nt++) {
        float b1o = out1_b[nt * 16 + l15];
        float o2  = out2_w[nt * 16 + l15];
        #pragma unroll
        for (int r = 0; r < 4; r++)
            part += ssp(ha[nt][r] + b1o) * o2;
    }
    #pragma unroll
    for (int off = 32; off > 0; off >>= 1) part += __shfl_down(part, off);
    if (lane == 0) atomicAdd(&s_red, part);
    __syncthreads();
    if (tid == 0) out[blockIdx.x] = s_red + 32.0f * out2_b[0];
}

extern "C" void kernel_launch(void* const* d_in, const int* in_sizes, int n_in,
                              void* d_out, int out_size, void* d_ws, size_t ws_size,
                              hipStream_t stream)
{
    const int*   z      = (const int*)d_in[0];
    const float* pos    = (const float*)d_in[1];
    const int*   eidx   = (const int*)d_in[3];
    const float* emb    = (const float*)d_in[4];
    const float* mlp_w1 = (const float*)d_in[5];
    const float* mlp_b1 = (const float*)d_in[6];
    const float* mlp_w2 = (const float*)d_in[7];
    const float* mlp_b2 = (const float*)d_in[8];
    const float* cf1_w  = (const float*)d_in[9];
    const float* cf2_w  = (const float*)d_in[10];
    const float* cf2_b  = (const float*)d_in[11];
    const float* lin_w  = (const float*)d_in[12];
    const float* lin_b  = (const float*)d_in[13];
    const float* out1_w = (const float*)d_in[14];
    const float* out1_b = (const float*)d_in[15];
    const float* out2_w = (const float*)d_in[16];
    const float* out2_b = (const float*)d_in[17];
    const int E = in_sizes[3] / 2;

    // workspace carve-up (16B-aligned sections)
    char* p = (char*)d_ws;
    uint2* ifr = (uint2*)p;                       p += ((size_t)E * 8 + 63) & ~63ULL;
    unsigned int* Tp = (unsigned int*)p;          p += (size_t)3 * KTAB * 128 * 4;
    int* rowptr = (int*)p;                        p += ((size_t)(NATOMS + 1) * 4 + 63) & ~63ULL;
    unsigned short* Ttab = (unsigned short*)p;    p += (size_t)3 * KTAB * 128 * 2;
    unsigned short* Wtall = (unsigned short*)p;   // 9*16384 + 64*128 ushorts

    rowptr_kernel<<<(NATOMS + 256) / 256, 256, 0, stream>>>(eidx, E, rowptr);
    prep_weights_kernel<<<(9 * 16384 + 64 * 128 + 255) / 256, 256, 0, stream>>>(
        cf1_w, cf2_w, lin_w, out1_w, Wtall);
    build_table_kernel<<<dim3(KTAB / 64, 3), 256, 0, stream>>>(
        mlp_w1, mlp_b1, mlp_w2, mlp_b2, Ttab);
    pack_table_kernel<<<3 * KTAB * 128 / 256, 256, 0, stream>>>(Ttab, Tp);
    edge_ifr_kernel<<<(E + 255) / 256, 256, 0, stream>>>(pos, eidx, E, ifr);

    fused_schnet_kernel<<<NMOL, 128, 0, stream>>>(
        z, emb, eidx + E, rowptr, ifr, Tp, Wtall,
        cf2_b, lin_b, out1_b, out2_w, out2_b, (float*)d_out);
}

// Round 7
// 207.545 us; speedup vs baseline: 12.1792x; 1.2937x over previous
//
#include <hip/hip_runtime.h>
#include <hip/hip_bf16.h>
#include <math.h>

// Problem constants (SchNet reference)
#define NATOMS 16384
#define NMOL   512
#define APM    32
#define GDIM   50
#define KTAB   2048   // filter lookup-table knots over d in [0,6]
#define MAXEPM 992    // max edges per molecule = 32*31

#define STRH 132      // s_h row stride (floats), 528B
#define STRA 136      // s_agg / s_t row stride (ushorts), 272B

typedef __attribute__((ext_vector_type(8))) short   short8;   // 8 bf16 (A/B frag)
typedef __attribute__((ext_vector_type(4))) float   floatx4;  // C/D frag

// fast shifted softplus: log(1+exp(x)) - log2, via HW v_exp_f32/v_log_f32
__device__ __forceinline__ float ssp(float x) {
    float e = __expf(-fabsf(x));
    return fmaxf(x, 0.0f) + __logf(1.0f + e) - 0.69314718055994531f;
}

__device__ __forceinline__ unsigned short f2bf(float x) {
    union { float f; unsigned int u; } v; v.f = x;
    unsigned int lsb = (v.u >> 16) & 1u;
    v.u += 0x7fffu + lsb;
    return (unsigned short)(v.u >> 16);
}

__device__ __forceinline__ unsigned int pk2bf(float a, float b) {
    __hip_bfloat162 h = __float22bfloat162_rn(make_float2(a, b));
    unsigned int u;
    __builtin_memcpy(&u, &h, 4);
    return u;
}

__device__ __forceinline__ float bf2f(unsigned int u16bits) {
    union { unsigned int u; float f; } v; v.u = u16bits << 16;
    return v.f;
}

// ---------------------------------------------------------------------------
// Merged setup: per-edge packed meta {knot<<5 | dst&31, frac}, rowptr,
// bf16 B-frag weight transposes (9x128x128 + out1 64x128). One dispatch.
// ---------------------------------------------------------------------------
__global__ __launch_bounds__(256) void setup_kernel(
    const float* __restrict__ pos, const int* __restrict__ eidx, int E,
    int* __restrict__ rowptr,
    const float* __restrict__ cf1, const float* __restrict__ cf2,
    const float* __restrict__ lin, const float* __restrict__ out1,
    unsigned short* __restrict__ Wtall, uint2* __restrict__ meta)
{
    int idx = blockIdx.x * 256 + threadIdx.x;
    if (idx < E) {
        int s = eidx[idx], t = eidx[E + idx];
        float dx = pos[3 * s]     - pos[3 * t];
        float dy = pos[3 * s + 1] - pos[3 * t + 1];
        float dz = pos[3 * s + 2] - pos[3 * t + 2];
        float d  = sqrtf(dx * dx + dy * dy + dz * dz);
        float u  = d * (float)(KTAB - 1) / 6.0f;
        int i = min((int)u, KTAB - 2);
        float frac = u - (float)i;
        meta[idx] = make_uint2(((unsigned)i << 5) | (unsigned)(t & 31),
                               __float_as_uint(frac));
    } else if (idx < E + NATOMS + 1) {
        int a = idx - E;
        int lo = 0, hi = E;
        while (lo < hi) { int mid = (lo + hi) >> 1; if (eidx[mid] < a) lo = mid + 1; else hi = mid; }
        rowptr[a] = lo;
    } else if (idx < E + NATOMS + 1 + 9 * 16384 + 64 * 128) {
        int r = idx - (E + NATOMS + 1);
        if (r < 9 * 16384) {
            int wi = r >> 14, rem = r & 16383;
            int n = rem >> 7, k = rem & 127;
            int l = wi / 3, which = wi % 3;
            const float* src = (which == 0) ? cf1 : (which == 1) ? cf2 : lin;
            Wtall[r] = f2bf(src[(size_t)l * 16384 + k * 128 + n]);
        } else {
            int q = r - 9 * 16384;
            int n = q >> 7, k = q & 127;
            Wtall[r] = f2bf(out1[k * 64 + n]);
        }
    }
}

// ---------------------------------------------------------------------------
// Build filter table: T[l][k][f] = ((ssp(ea(d_k)@w1+b1)@w2)+b2)*cut(d_k), bf16
// ---------------------------------------------------------------------------
#define KW1 72
#define KW2 136

__global__ __launch_bounds__(256, 2) void build_table_kernel(
    const float* __restrict__ w1_, const float* __restrict__ b1_,
    const float* __restrict__ w2_, const float* __restrict__ b2_,
    unsigned short* __restrict__ T_)
{
    const int l = blockIdx.y;
    const float* w1 = w1_ + (size_t)l * GDIM * 128;
    const float* b1 = b1_ + (size_t)l * 128;
    const float* w2 = w2_ + (size_t)l * 128 * 128;
    const float* b2 = b2_ + (size_t)l * 128;
    unsigned short* T = T_ + (size_t)l * KTAB * 128;

    __shared__ unsigned short s_w1T[128 * KW1];
    __shared__ unsigned short s_w2T[128 * KW2];
    __shared__ unsigned short s_t[64 * KW2];

    const int tid = threadIdx.x;
    for (int i = tid; i < GDIM * 128; i += 256) {
        int g = i >> 7, f = i & 127;
        s_w1T[f * KW1 + g] = f2bf(w1[i]);
    }
    for (int i = tid; i < (64 - GDIM) * 128; i += 256) {
        int g = GDIM + (i >> 7), f = i & 127;
        s_w1T[f * KW1 + g] = 0;
    }
    for (int i = tid; i < 128 * 128; i += 256) {
        int k = i >> 7, n = i & 127;
        s_w2T[n * KW2 + k] = f2bf(w2[i]);
    }

    const int lane = tid & 63;
    const int w    = tid >> 6;
    const int l15  = lane & 15;
    const int quad = lane >> 4;

    float b1v[8], b2v[8];
    #pragma unroll
    for (int nt = 0; nt < 8; nt++) {
        b1v[nt] = b1[nt * 16 + l15];
        b2v[nt] = b2[nt * 16 + l15];
    }
    __syncthreads();

    const float hstep = 6.0f / (float)(KTAB - 1);
    const float step  = 6.0f / 49.0f;
    const float coeff = -0.5f / (step * step);
    const float pioc  = 3.14159265358979323846f / 6.0f;
    const int k0 = blockIdx.x * 64;
    const float dm = (float)(k0 + w * 16 + l15) * hstep;

    floatx4 acc1[8];
    #pragma unroll
    for (int nt = 0; nt < 8; nt++) acc1[nt] = (floatx4){0.f, 0.f, 0.f, 0.f};
    #pragma unroll
    for (int ks = 0; ks < 2; ks++) {
        unsigned int ap[4];
        #pragma unroll
        for (int jj = 0; jj < 4; jj++) {
            int g0 = ks * 32 + quad * 8 + 2 * jj;
            float d0 = dm - (float)g0 * step;
            float d1 = dm - (float)(g0 + 1) * step;
            float v0 = (g0 < GDIM)     ? __expf(coeff * d0 * d0) : 0.0f;
            float v1 = (g0 + 1 < GDIM) ? __expf(coeff * d1 * d1) : 0.0f;
            ap[jj] = pk2bf(v0, v1);
        }
        short8 af;
        __builtin_memcpy(&af, ap, 16);
        #pragma unroll
        for (int nt = 0; nt < 8; nt++) {
            short8 bfg = *(const short8*)&s_w1T[(nt * 16 + l15) * KW1 + ks * 32 + quad * 8];
            acc1[nt] = __builtin_amdgcn_mfma_f32_16x16x32_bf16(af, bfg, acc1[nt], 0, 0, 0);
        }
    }
    #pragma unroll
    for (int nt = 0; nt < 8; nt++) {
        #pragma unroll
        for (int r = 0; r < 4; r++) {
            int row = w * 16 + quad * 4 + r;
            s_t[row * KW2 + nt * 16 + l15] = f2bf(ssp(acc1[nt][r] + b1v[nt]));
        }
    }
    // no barrier: wave reads only rows it wrote

    floatx4 acc2[8];
    #pragma unroll
    for (int nt = 0; nt < 8; nt++) acc2[nt] = (floatx4){0.f, 0.f, 0.f, 0.f};
    #pragma unroll
    for (int ks = 0; ks < 4; ks++) {
        short8 af = *(const short8*)&s_t[(w * 16 + l15) * KW2 + ks * 32 + quad * 8];
        #pragma unroll
        for (int nt = 0; nt < 8; nt++) {
            short8 bfg = *(const short8*)&s_w2T[(nt * 16 + l15) * KW2 + ks * 32 + quad * 8];
            acc2[nt] = __builtin_amdgcn_mfma_f32_16x16x32_bf16(af, bfg, acc2[nt], 0, 0, 0);
        }
    }

    #pragma unroll
    for (int nt = 0; nt < 8; nt++) {
        #pragma unroll
        for (int r = 0; r < 4; r++) {
            int row = w * 16 + quad * 4 + r;
            float d = (float)(k0 + row) * hstep;
            float cut = 0.5f * (__cosf(d * pioc) + 1.0f);
            T[(size_t)(k0 + row) * 128 + nt * 16 + l15] = f2bf((acc2[nt][r] + b2v[nt]) * cut);
        }
    }
}

// pack neighbor knots: Tp[l][k][f] = (T[k][f] , T[k+1][f]) as bf16x2 in a uint
__global__ __launch_bounds__(256) void pack_table_kernel(
    const unsigned short* __restrict__ T, unsigned int* __restrict__ Tp)
{
    int idx = blockIdx.x * 256 + threadIdx.x;    // over 3*KTAB*128
    int k = (idx >> 7) & (KTAB - 1);
    unsigned int lo = T[idx];
    unsigned int hi = (k == KTAB - 1) ? lo : T[idx + 128];
    Tp[idx] = lo | (hi << 16);
}

// ---------------------------------------------------------------------------
// Fully-fused SchNet: one block = one molecule, 256 threads = 4 waves.
// Wave w owns GEMM quadrant rows (w&1)*16, cols (w>>1)*64; gather atoms
// w*8..w*8+8. Edge metadata staged in LDS once; gather inner loop does a
// single 8B global load (lerp-table row slice) per edge, 8-deep unrolled.
// ---------------------------------------------------------------------------
__global__ __launch_bounds__(256) void fused_schnet_kernel(
    const int* __restrict__ z, const float* __restrict__ emb,
    const int* __restrict__ rowptr, const uint2* __restrict__ meta,
    const unsigned int* __restrict__ Tp,
    const unsigned short* __restrict__ Wtall,
    const float* __restrict__ cf2_b, const float* __restrict__ lin_b,
    const float* __restrict__ out1_b, const float* __restrict__ out2_w,
    const float* __restrict__ out2_b,
    float* __restrict__ out)
{
    __shared__ float s_h[32 * STRH];                 // 16.9 KB fp32 node state
    __shared__ float s_hx[32 * 128];                 // 16.4 KB (aliased by s_t)
    __shared__ unsigned short s_agg[32 * STRA];      //  8.7 KB
    __shared__ uint2 s_meta[MAXEPM];                 //  7.9 KB
    __shared__ float s_red;
    unsigned short* s_t = (unsigned short*)s_hx;     // [32][STRA] bf16 alias

    const int tid  = threadIdx.x;
    const int lane = tid & 63;
    const int w    = tid >> 6;          // wave 0..3
    const int l15  = lane & 15;
    const int quad = lane >> 4;
    const int r16  = (w & 1) * 16;      // GEMM row tile
    const int c64  = (w >> 1) * 64;     // GEMM col tile
    const int B0   = blockIdx.x * 32;   // molecule base atom

    // init h from embedding
    for (int i = tid; i < 32 * 128; i += 256) {
        int row = i >> 7, col = i & 127;
        s_h[row * STRH + col] = emb[(size_t)z[B0 + row] * 128 + col];
    }
    if (tid == 0) s_red = 0.0f;

    // stage this molecule's edge metadata into LDS (layer-invariant)
    const int ebase = rowptr[B0];
    const int nE    = rowptr[B0 + 32] - ebase;
    for (int i = tid; i < nE; i += 256) s_meta[i] = meta[ebase + i];

    // local row pointers for this wave's 8 atoms (9 bounds in lanes 0..8)
    const int rp = rowptr[B0 + w * 8 + min(lane, 8)] - ebase;

    const unsigned short* WtO = Wtall + 9 * 16384;   // out1^T

    for (int l = 0; l < 3; l++) {
        const unsigned short* W1 = Wtall + (size_t)(l * 3 + 0) * 16384;
        const unsigned short* W2 = Wtall + (size_t)(l * 3 + 1) * 16384;
        const unsigned short* W3 = Wtall + (size_t)(l * 3 + 2) * 16384;
        const unsigned int* Tpl  = Tp + (size_t)l * KTAB * 128;

        __syncthreads();   // h ready (also covers meta staging at l=0)

        // ---- GEMM1: hx = h @ cf1 (quadrant per wave) ----
        floatx4 acc[4];
        #pragma unroll
        for (int nt = 0; nt < 4; nt++) acc[nt] = (floatx4){0.f, 0.f, 0.f, 0.f};
        #pragma unroll
        for (int ks = 0; ks < 4; ks++) {
            const float* hp = &s_h[(r16 + l15) * STRH + ks * 32 + quad * 8];
            float4 xa = *(const float4*)hp;
            float4 xb = *(const float4*)(hp + 4);
            unsigned int ap[4];
            ap[0] = pk2bf(xa.x, xa.y); ap[1] = pk2bf(xa.z, xa.w);
            ap[2] = pk2bf(xb.x, xb.y); ap[3] = pk2bf(xb.z, xb.w);
            short8 af;
            __builtin_memcpy(&af, ap, 16);
            #pragma unroll
            for (int nt = 0; nt < 4; nt++) {
                short8 bfg = *(const short8*)&W1[(size_t)(c64 + nt * 16 + l15) * 128 + ks * 32 + quad * 8];
                acc[nt] = __builtin_amdgcn_mfma_f32_16x16x32_bf16(af, bfg, acc[nt], 0, 0, 0);
            }
        }
        #pragma unroll
        for (int nt = 0; nt < 4; nt++) {
            #pragma unroll
            for (int r = 0; r < 4; r++)
                s_hx[(r16 + quad * 4 + r) * 128 + c64 + nt * 16 + l15] = acc[nt][r];
        }

        __syncthreads();   // hx complete before gather reads

        // ---- gather + lerp (wave per atom-group of 8) ----
        for (int al = 0; al < 8; al++) {
            const int e0 = __shfl(rp, al);
            const int e1 = __shfl(rp, al + 1);
            float ax[8], ay[8];
            #pragma unroll
            for (int j = 0; j < 8; j++) { ax[j] = 0.f; ay[j] = 0.f; }
            int e = e0;
            for (; e + 7 < e1; e += 8) {
                #pragma unroll
                for (int j = 0; j < 8; j++) {
                    uint2 q = s_meta[e + j];
                    int tl   = q.x & 31;
                    int knot = q.x >> 5;
                    uint2 tp = *(const uint2*)&Tpl[(size_t)knot * 128 + 2 * lane];
                    float2 hv = *(const float2*)&s_hx[tl * 128 + 2 * lane];
                    float fr = __uint_as_float(q.y);
                    float w0 = bf2f(tp.x & 0xffffu), w1 = bf2f(tp.x >> 16);
                    ax[j] = fmaf(hv.x, fmaf(fr, w1 - w0, w0), ax[j]);
                    w0 = bf2f(tp.y & 0xffffu); w1 = bf2f(tp.y >> 16);
                    ay[j] = fmaf(hv.y, fmaf(fr, w1 - w0, w0), ay[j]);
                }
            }
            for (; e < e1; e++) {
                int j = (e - e0) & 7;
                uint2 q = s_meta[e];
                int tl   = q.x & 31;
                int knot = q.x >> 5;
                uint2 tp = *(const uint2*)&Tpl[(size_t)knot * 128 + 2 * lane];
                float2 hv = *(const float2*)&s_hx[tl * 128 + 2 * lane];
                float fr = __uint_as_float(q.y);
                float w0 = bf2f(tp.x & 0xffffu), w1 = bf2f(tp.x >> 16);
                ax[j] = fmaf(hv.x, fmaf(fr, w1 - w0, w0), ax[j]);
                w0 = bf2f(tp.y & 0xffffu); w1 = bf2f(tp.y >> 16);
                ay[j] = fmaf(hv.y, fmaf(fr, w1 - w0, w0), ay[j]);
            }
            float sx = ((ax[0] + ax[1]) + (ax[2] + ax[3])) + ((ax[4] + ax[5]) + (ax[6] + ax[7]));
            float sy = ((ay[0] + ay[1]) + (ay[2] + ay[3])) + ((ay[4] + ay[5]) + (ay[6] + ay[7]));
            *(unsigned int*)&s_agg[(w * 8 + al) * STRA + 2 * lane] = pk2bf(sx, sy);
        }

        __syncthreads();   // agg complete; s_hx reads done (s_t alias safe)

        // ---- GEMM2: t = ssp(agg @ cf2 + b) ----
        float bva[4], bvb[4];
        #pragma unroll
        for (int nt = 0; nt < 4; nt++) {
            bva[nt] = cf2_b[l * 128 + c64 + nt * 16 + l15];
            bvb[nt] = lin_b[l * 128 + c64 + nt * 16 + l15];
        }
        #pragma unroll
        for (int nt = 0; nt < 4; nt++) acc[nt] = (floatx4){0.f, 0.f, 0.f, 0.f};
        #pragma unroll
        for (int ks = 0; ks < 4; ks++) {
            short8 af = *(const short8*)&s_agg[(r16 + l15) * STRA + ks * 32 + quad * 8];
            #pragma unroll
            for (int nt = 0; nt < 4; nt++) {
                short8 bfg = *(const short8*)&W2[(size_t)(c64 + nt * 16 + l15) * 128 + ks * 32 + quad * 8];
                acc[nt] = __builtin_amdgcn_mfma_f32_16x16x32_bf16(af, bfg, acc[nt], 0, 0, 0);
            }
        }
        #pragma unroll
        for (int nt = 0; nt < 4; nt++) {
            #pragma unroll
            for (int r = 0; r < 4; r++) {
                int row = r16 + quad * 4 + r;
                s_t[row * STRA + c64 + nt * 16 + l15] = f2bf(ssp(acc[nt][r] + bva[nt]));
            }
        }

        __syncthreads();   // t complete (cross-wave cols needed by GEMM3)

        // ---- GEMM3: h += t @ lin + b ----
        #pragma unroll
        for (int nt = 0; nt < 4; nt++) acc[nt] = (floatx4){0.f, 0.f, 0.f, 0.f};
        #pragma unroll
        for (int ks = 0; ks < 4; ks++) {
            short8 af = *(const short8*)&s_t[(r16 + l15) * STRA + ks * 32 + quad * 8];
            #pragma unroll
            for (int nt = 0; nt < 4; nt++) {
                short8 bfg = *(const short8*)&W3[(size_t)(c64 + nt * 16 + l15) * 128 + ks * 32 + quad * 8];
                acc[nt] = __builtin_amdgcn_mfma_f32_16x16x32_bf16(af, bfg, acc[nt], 0, 0, 0);
            }
        }
        #pragma unroll
        for (int nt = 0; nt < 4; nt++) {
            #pragma unroll
            for (int r = 0; r < 4; r++) {
                int row = r16 + quad * 4 + r;
                s_h[row * STRH + c64 + nt * 16 + l15] += acc[nt][r] + bvb[nt];
            }
        }
        // loop-top __syncthreads covers h
    }

    __syncthreads();

    // ---- head: out = sum_a ssp(h@out1 + b1)@out2 + 32*b2 ----
    const int c32 = (w >> 1) * 32;
    floatx4 ha[2];
    #pragma unroll
    for (int nt = 0; nt < 2; nt++) ha[nt] = (floatx4){0.f, 0.f, 0.f, 0.f};
    #pragma unroll
    for (int ks = 0; ks < 4; ks++) {
        const float* hp = &s_h[(r16 + l15) * STRH + ks * 32 + quad * 8];
        float4 xa = *(const float4*)hp;
        float4 xb = *(const float4*)(hp + 4);
        unsigned int ap[4];
        ap[0] = pk2bf(xa.x, xa.y); ap[1] = pk2bf(xa.z, xa.w);
        ap[2] = pk2bf(xb.x, xb.y); ap[3] = pk2bf(xb.z, xb.w);
        short8 af;
        __builtin_memcpy(&af, ap, 16);
        #pragma unroll
        for (int nt = 0; nt < 2; nt++) {
            short8 bfg = *(const short8*)&WtO[(size_t)(c32 + nt * 16 + l15) * 128 + ks * 32 + quad * 8];
            ha[nt] = __builtin_amdgcn_mfma_f32_16x16x32_bf16(af, bfg, ha[nt], 0, 0, 0);
        }
    }
    float part = 0.0f;
    #pragma unroll
    for (int nt = 0; nt < 2; nt++) {
        float b1o = out1_b[c32 + nt * 16 + l15];
        float o2  = out2_w[c32 + nt * 16 + l15];
        #pragma unroll
        for (int r = 0; r < 4; r++)
            part += ssp(ha[nt][r] + b1o) * o2;
    }
    #pragma unroll
    for (int off = 32; off > 0; off >>= 1) part += __shfl_down(part, off);
    if (lane == 0) atomicAdd(&s_red, part);
    __syncthreads();
    if (tid == 0) out[blockIdx.x] = s_red + 32.0f * out2_b[0];
}

extern "C" void kernel_launch(void* const* d_in, const int* in_sizes, int n_in,
                              void* d_out, int out_size, void* d_ws, size_t ws_size,
                              hipStream_t stream)
{
    const int*   z      = (const int*)d_in[0];
    const float* pos    = (const float*)d_in[1];
    const int*   eidx   = (const int*)d_in[3];
    const float* emb    = (const float*)d_in[4];
    const float* mlp_w1 = (const float*)d_in[5];
    const float* mlp_b1 = (const float*)d_in[6];
    const float* mlp_w2 = (const float*)d_in[7];
    const float* mlp_b2 = (const float*)d_in[8];
    const float* cf1_w  = (const float*)d_in[9];
    const float* cf2_w  = (const float*)d_in[10];
    const float* cf2_b  = (const float*)d_in[11];
    const float* lin_w  = (const float*)d_in[12];
    const float* lin_b  = (const float*)d_in[13];
    const float* out1_w = (const float*)d_in[14];
    const float* out1_b = (const float*)d_in[15];
    const float* out2_w = (const float*)d_in[16];
    const float* out2_b = (const float*)d_in[17];
    const int E = in_sizes[3] / 2;

    // workspace carve-up (16B-aligned sections)
    char* p = (char*)d_ws;
    uint2* meta = (uint2*)p;                      p += ((size_t)E * 8 + 63) & ~63ULL;
    unsigned int* Tp = (unsigned int*)p;          p += (size_t)3 * KTAB * 128 * 4;
    int* rowptr = (int*)p;                        p += ((size_t)(NATOMS + 1) * 4 + 63) & ~63ULL;
    unsigned short* Ttab = (unsigned short*)p;    p += (size_t)3 * KTAB * 128 * 2;
    unsigned short* Wtall = (unsigned short*)p;   // 9*16384 + 64*128 ushorts

    const int setup_work = E + (NATOMS + 1) + 9 * 16384 + 64 * 128;
    setup_kernel<<<(setup_work + 255) / 256, 256, 0, stream>>>(
        pos, eidx, E, rowptr, cf1_w, cf2_w, lin_w, out1_w, Wtall, meta);
    build_table_kernel<<<dim3(KTAB / 64, 3), 256, 0, stream>>>(
        mlp_w1, mlp_b1, mlp_w2, mlp_b2, Ttab);
    pack_table_kernel<<<3 * KTAB * 128 / 256, 256, 0, stream>>>(Ttab, Tp);

    fused_schnet_kernel<<<NMOL, 256, 0, stream>>>(
        z, emb, rowptr, meta, Tp, Wtall,
        cf2_b, lin_b, out1_b, out2_w, out2_b, (float*)d_out);
}

// Round 8
// 187.353 us; speedup vs baseline: 13.4918x; 1.1078x over previous
//
#include <hip/hip_runtime.h>
#include <hip/hip_bf16.h>
#include <math.h>

// Problem constants (SchNet reference)
#define NATOMS 16384
#define NMOL   512
#define APM    32
#define GDIM   50
#define KTAB   2048   // filter lookup-table knots over d in [0,6]
#define MAXEPM 992    // max edges per molecule = 32*31

#define STRH 132      // s_h row stride (floats), 528B
#define STRA 136      // s_agg / s_t row stride (ushorts), 272B

typedef __attribute__((ext_vector_type(8))) short   short8;   // 8 bf16 (A/B frag)
typedef __attribute__((ext_vector_type(4))) float   floatx4;  // C/D frag

// fast shifted softplus: log(1+exp(x)) - log2, via HW v_exp_f32/v_log_f32
__device__ __forceinline__ float ssp(float x) {
    float e = __expf(-fabsf(x));
    return fmaxf(x, 0.0f) + __logf(1.0f + e) - 0.69314718055994531f;
}

__device__ __forceinline__ unsigned short f2bf(float x) {
    union { float f; unsigned int u; } v; v.f = x;
    unsigned int lsb = (v.u >> 16) & 1u;
    v.u += 0x7fffu + lsb;
    return (unsigned short)(v.u >> 16);
}

__device__ __forceinline__ unsigned int pk2bf(float a, float b) {
    __hip_bfloat162 h = __float22bfloat162_rn(make_float2(a, b));
    unsigned int u;
    __builtin_memcpy(&u, &h, 4);
    return u;
}

// ---------------------------------------------------------------------------
// Merged setup: per-edge packed meta {knot<<5 | dst&31, frac}, rowptr,
// bf16 B-frag weight transposes (9x128x128 + out1 64x128). One dispatch.
// ---------------------------------------------------------------------------
__global__ __launch_bounds__(256) void setup_kernel(
    const float* __restrict__ pos, const int* __restrict__ eidx, int E,
    int* __restrict__ rowptr,
    const float* __restrict__ cf1, const float* __restrict__ cf2,
    const float* __restrict__ lin, const float* __restrict__ out1,
    unsigned short* __restrict__ Wtall, uint2* __restrict__ meta)
{
    int idx = blockIdx.x * 256 + threadIdx.x;
    if (idx < E) {
        int s = eidx[idx], t = eidx[E + idx];
        float dx = pos[3 * s]     - pos[3 * t];
        float dy = pos[3 * s + 1] - pos[3 * t + 1];
        float dz = pos[3 * s + 2] - pos[3 * t + 2];
        float d  = sqrtf(dx * dx + dy * dy + dz * dz);
        float u  = d * (float)(KTAB - 1) / 6.0f;
        int i = min((int)u, KTAB - 2);
        float frac = u - (float)i;
        meta[idx] = make_uint2(((unsigned)i << 5) | (unsigned)(t & 31),
                               __float_as_uint(frac));
    } else if (idx < E + NATOMS + 1) {
        int a = idx - E;
        int lo = 0, hi = E;
        while (lo < hi) { int mid = (lo + hi) >> 1; if (eidx[mid] < a) lo = mid + 1; else hi = mid; }
        rowptr[a] = lo;
    } else if (idx < E + NATOMS + 1 + 9 * 16384 + 64 * 128) {
        int r = idx - (E + NATOMS + 1);
        if (r < 9 * 16384) {
            int wi = r >> 14, rem = r & 16383;
            int n = rem >> 7, k = rem & 127;
            int l = wi / 3, which = wi % 3;
            const float* src = (which == 0) ? cf1 : (which == 1) ? cf2 : lin;
            Wtall[r] = f2bf(src[(size_t)l * 16384 + k * 128 + n]);
        } else {
            int q = r - 9 * 16384;
            int n = q >> 7, k = q & 127;
            Wtall[r] = f2bf(out1[k * 64 + n]);
        }
    }
}

// ---------------------------------------------------------------------------
// Build filter table: T[l][k][f] = ((ssp(ea(d_k)@w1+b1)@w2)+b2)*cut(d_k), bf16
// ---------------------------------------------------------------------------
#define KW1 72
#define KW2 136

__global__ __launch_bounds__(256, 2) void build_table_kernel(
    const float* __restrict__ w1_, const float* __restrict__ b1_,
    const float* __restrict__ w2_, const float* __restrict__ b2_,
    unsigned short* __restrict__ T_)
{
    const int l = blockIdx.y;
    const float* w1 = w1_ + (size_t)l * GDIM * 128;
    const float* b1 = b1_ + (size_t)l * 128;
    const float* w2 = w2_ + (size_t)l * 128 * 128;
    const float* b2 = b2_ + (size_t)l * 128;
    unsigned short* T = T_ + (size_t)l * KTAB * 128;

    __shared__ unsigned short s_w1T[128 * KW1];
    __shared__ unsigned short s_w2T[128 * KW2];
    __shared__ unsigned short s_t[64 * KW2];

    const int tid = threadIdx.x;
    for (int i = tid; i < GDIM * 128; i += 256) {
        int g = i >> 7, f = i & 127;
        s_w1T[f * KW1 + g] = f2bf(w1[i]);
    }
    for (int i = tid; i < (64 - GDIM) * 128; i += 256) {
        int g = GDIM + (i >> 7), f = i & 127;
        s_w1T[f * KW1 + g] = 0;
    }
    for (int i = tid; i < 128 * 128; i += 256) {
        int k = i >> 7, n = i & 127;
        s_w2T[n * KW2 + k] = f2bf(w2[i]);
    }

    const int lane = tid & 63;
    const int w    = tid >> 6;
    const int l15  = lane & 15;
    const int quad = lane >> 4;

    float b1v[8], b2v[8];
    #pragma unroll
    for (int nt = 0; nt < 8; nt++) {
        b1v[nt] = b1[nt * 16 + l15];
        b2v[nt] = b2[nt * 16 + l15];
    }
    __syncthreads();

    const float hstep = 6.0f / (float)(KTAB - 1);
    const float step  = 6.0f / 49.0f;
    const float coeff = -0.5f / (step * step);
    const float pioc  = 3.14159265358979323846f / 6.0f;
    const int k0 = blockIdx.x * 64;
    const float dm = (float)(k0 + w * 16 + l15) * hstep;

    floatx4 acc1[8];
    #pragma unroll
    for (int nt = 0; nt < 8; nt++) acc1[nt] = (floatx4){0.f, 0.f, 0.f, 0.f};
    #pragma unroll
    for (int ks = 0; ks < 2; ks++) {
        unsigned int ap[4];
        #pragma unroll
        for (int jj = 0; jj < 4; jj++) {
            int g0 = ks * 32 + quad * 8 + 2 * jj;
            float d0 = dm - (float)g0 * step;
            float d1 = dm - (float)(g0 + 1) * step;
            float v0 = (g0 < GDIM)     ? __expf(coeff * d0 * d0) : 0.0f;
            float v1 = (g0 + 1 < GDIM) ? __expf(coeff * d1 * d1) : 0.0f;
            ap[jj] = pk2bf(v0, v1);
        }
        short8 af;
        __builtin_memcpy(&af, ap, 16);
        #pragma unroll
        for (int nt = 0; nt < 8; nt++) {
            short8 bfg = *(const short8*)&s_w1T[(nt * 16 + l15) * KW1 + ks * 32 + quad * 8];
            acc1[nt] = __builtin_amdgcn_mfma_f32_16x16x32_bf16(af, bfg, acc1[nt], 0, 0, 0);
        }
    }
    #pragma unroll
    for (int nt = 0; nt < 8; nt++) {
        #pragma unroll
        for (int r = 0; r < 4; r++) {
            int row = w * 16 + quad * 4 + r;
            s_t[row * KW2 + nt * 16 + l15] = f2bf(ssp(acc1[nt][r] + b1v[nt]));
        }
    }
    // no barrier: wave reads only rows it wrote

    floatx4 acc2[8];
    #pragma unroll
    for (int nt = 0; nt < 8; nt++) acc2[nt] = (floatx4){0.f, 0.f, 0.f, 0.f};
    #pragma unroll
    for (int ks = 0; ks < 4; ks++) {
        short8 af = *(const short8*)&s_t[(w * 16 + l15) * KW2 + ks * 32 + quad * 8];
        #pragma unroll
        for (int nt = 0; nt < 8; nt++) {
            short8 bfg = *(const short8*)&s_w2T[(nt * 16 + l15) * KW2 + ks * 32 + quad * 8];
            acc2[nt] = __builtin_amdgcn_mfma_f32_16x16x32_bf16(af, bfg, acc2[nt], 0, 0, 0);
        }
    }

    #pragma unroll
    for (int nt = 0; nt < 8; nt++) {
        #pragma unroll
        for (int r = 0; r < 4; r++) {
            int row = w * 16 + quad * 4 + r;
            float d = (float)(k0 + row) * hstep;
            float cut = 0.5f * (__cosf(d * pioc) + 1.0f);
            T[(size_t)(k0 + row) * 128 + nt * 16 + l15] = f2bf((acc2[nt][r] + b2v[nt]) * cut);
        }
    }
}

// pack (w0, dw) knots: Tp[l][k][f] = T[k][f] | bf16(T[k+1][f]-T[k][f])<<16
__global__ __launch_bounds__(256) void pack_table_kernel(
    const unsigned short* __restrict__ T, unsigned int* __restrict__ Tp)
{
    int idx = blockIdx.x * 256 + threadIdx.x;    // over 3*KTAB*128
    int k = (idx >> 7) & (KTAB - 1);
    unsigned int w0 = T[idx];
    float w0f = __uint_as_float(w0 << 16);
    float w1f = (k == KTAB - 1) ? w0f
              : __uint_as_float((unsigned int)T[idx + 128] << 16);
    unsigned int dw = f2bf(w1f - w0f);
    Tp[idx] = w0 | (dw << 16);
}

// ---------------------------------------------------------------------------
// Fully-fused SchNet: one block = one molecule, 512 threads = 8 waves
// (2 blocks/CU -> 16 waves/CU for latency hiding; LDS ~50KB/block).
// Wave w: GEMM tile rows (w&1)*16, cols (w>>1)*32; gather atoms w*4..w*4+4.
// Edge metadata staged in LDS; gather inner loop = one 8B global load
// (packed (w0,dw) lerp-table slice) per edge, 8-deep unrolled.
// ---------------------------------------------------------------------------
__global__ __launch_bounds__(512) void fused_schnet_kernel(
    const int* __restrict__ z, const float* __restrict__ emb,
    const int* __restrict__ rowptr, const uint2* __restrict__ meta,
    const unsigned int* __restrict__ Tp,
    const unsigned short* __restrict__ Wtall,
    const float* __restrict__ cf2_b, const float* __restrict__ lin_b,
    const float* __restrict__ out1_b, const float* __restrict__ out2_w,
    const float* __restrict__ out2_b,
    float* __restrict__ out)
{
    __shared__ float s_h[32 * STRH];                 // 16.9 KB fp32 node state
    __shared__ float s_hx[32 * 128];                 // 16.4 KB (aliased by s_t)
    __shared__ unsigned short s_agg[32 * STRA];      //  8.7 KB
    __shared__ uint2 s_meta[MAXEPM];                 //  7.9 KB
    __shared__ float s_red;
    unsigned short* s_t = (unsigned short*)s_hx;     // [32][STRA] bf16 alias

    const int tid  = threadIdx.x;
    const int lane = tid & 63;
    const int w    = tid >> 6;          // wave 0..7
    const int l15  = lane & 15;
    const int quad = lane >> 4;
    const int r16  = (w & 1) * 16;      // GEMM row tile
    const int c32  = (w >> 1) * 32;     // GEMM col tile (4 col tiles)
    const int B0   = blockIdx.x * 32;   // molecule base atom

    // init h from embedding
    for (int i = tid; i < 32 * 128; i += 512) {
        int row = i >> 7, col = i & 127;
        s_h[row * STRH + col] = emb[(size_t)z[B0 + row] * 128 + col];
    }
    if (tid == 0) s_red = 0.0f;

    // stage this molecule's edge metadata into LDS (layer-invariant)
    const int ebase = rowptr[B0];
    const int nE    = rowptr[B0 + 32] - ebase;
    for (int i = tid; i < nE; i += 512) s_meta[i] = meta[ebase + i];

    // local row pointers for this wave's 4 atoms (5 bounds in lanes 0..4)
    const int rp = rowptr[B0 + w * 4 + min(lane, 4)] - ebase;

    const unsigned short* WtO = Wtall + 9 * 16384;   // out1^T

    for (int l = 0; l < 3; l++) {
        const unsigned short* W1 = Wtall + (size_t)(l * 3 + 0) * 16384;
        const unsigned short* W2 = Wtall + (size_t)(l * 3 + 1) * 16384;
        const unsigned short* W3 = Wtall + (size_t)(l * 3 + 2) * 16384;
        const unsigned int* Tpl  = Tp + (size_t)l * KTAB * 128;

        __syncthreads();   // h ready (also covers meta staging at l=0)

        // ---- GEMM1: hx = h @ cf1 (16x32 octant per wave) ----
        floatx4 acc[2];
        #pragma unroll
        for (int nt = 0; nt < 2; nt++) acc[nt] = (floatx4){0.f, 0.f, 0.f, 0.f};
        #pragma unroll
        for (int ks = 0; ks < 4; ks++) {
            const float* hp = &s_h[(r16 + l15) * STRH + ks * 32 + quad * 8];
            float4 xa = *(const float4*)hp;
            float4 xb = *(const float4*)(hp + 4);
            unsigned int ap[4];
            ap[0] = pk2bf(xa.x, xa.y); ap[1] = pk2bf(xa.z, xa.w);
            ap[2] = pk2bf(xb.x, xb.y); ap[3] = pk2bf(xb.z, xb.w);
            short8 af;
            __builtin_memcpy(&af, ap, 16);
            #pragma unroll
            for (int nt = 0; nt < 2; nt++) {
                short8 bfg = *(const short8*)&W1[(size_t)(c32 + nt * 16 + l15) * 128 + ks * 32 + quad * 8];
                acc[nt] = __builtin_amdgcn_mfma_f32_16x16x32_bf16(af, bfg, acc[nt], 0, 0, 0);
            }
        }
        #pragma unroll
        for (int nt = 0; nt < 2; nt++) {
            #pragma unroll
            for (int r = 0; r < 4; r++)
                s_hx[(r16 + quad * 4 + r) * 128 + c32 + nt * 16 + l15] = acc[nt][r];
        }

        __syncthreads();   // hx complete before gather reads

        // ---- gather + lerp (wave per atom-group of 4) ----
        for (int al = 0; al < 4; al++) {
            const int e0 = __shfl(rp, al);
            const int e1 = __shfl(rp, al + 1);
            float ax[8], ay[8];
            #pragma unroll
            for (int j = 0; j < 8; j++) { ax[j] = 0.f; ay[j] = 0.f; }
            int e = e0;
            for (; e + 7 < e1; e += 8) {
                #pragma unroll
                for (int j = 0; j < 8; j++) {
                    uint2 q = s_meta[e + j];
                    int tl   = q.x & 31;
                    int knot = q.x >> 5;
                    uint2 tp = *(const uint2*)&Tpl[(size_t)knot * 128 + 2 * lane];
                    float2 hv = *(const float2*)&s_hx[tl * 128 + 2 * lane];
                    float fr = __uint_as_float(q.y);
                    float wx = fmaf(fr, __uint_as_float(tp.x & 0xffff0000u),
                                    __uint_as_float(tp.x << 16));
                    float wy = fmaf(fr, __uint_as_float(tp.y & 0xffff0000u),
                                    __uint_as_float(tp.y << 16));
                    ax[j] = fmaf(hv.x, wx, ax[j]);
                    ay[j] = fmaf(hv.y, wy, ay[j]);
                }
            }
            for (; e < e1; e++) {
                int j = (e - e0) & 7;
                uint2 q = s_meta[e];
                int tl   = q.x & 31;
                int knot = q.x >> 5;
                uint2 tp = *(const uint2*)&Tpl[(size_t)knot * 128 + 2 * lane];
                float2 hv = *(const float2*)&s_hx[tl * 128 + 2 * lane];
                float fr = __uint_as_float(q.y);
                float wx = fmaf(fr, __uint_as_float(tp.x & 0xffff0000u),
                                __uint_as_float(tp.x << 16));
                float wy = fmaf(fr, __uint_as_float(tp.y & 0xffff0000u),
                                __uint_as_float(tp.y << 16));
                ax[j] = fmaf(hv.x, wx, ax[j]);
                ay[j] = fmaf(hv.y, wy, ay[j]);
            }
            float sx = ((ax[0] + ax[1]) + (ax[2] + ax[3])) + ((ax[4] + ax[5]) + (ax[6] + ax[7]));
            float sy = ((ay[0] + ay[1]) + (ay[2] + ay[3])) + ((ay[4] + ay[5]) + (ay[6] + ay[7]));
            *(unsigned int*)&s_agg[(w * 4 + al) * STRA + 2 * lane] = pk2bf(sx, sy);
        }

        __syncthreads();   // agg complete; s_hx reads done (s_t alias safe)

        // ---- GEMM2: t = ssp(agg @ cf2 + b) ----
        float bva[2], bvb[2];
        #pragma unroll
        for (int nt = 0; nt < 2; nt++) {
            bva[nt] = cf2_b[l * 128 + c32 + nt * 16 + l15];
            bvb[nt] = lin_b[l * 128 + c32 + nt * 16 + l15];
        }
        #pragma unroll
        for (int nt = 0; nt < 2; nt++) acc[nt] = (floatx4){0.f, 0.f, 0.f, 0.f};
        #pragma unroll
        for (int ks = 0; ks < 4; ks++) {
            short8 af = *(const short8*)&s_agg[(r16 + l15) * STRA + ks * 32 + quad * 8];
            #pragma unroll
            for (int nt = 0; nt < 2; nt++) {
                short8 bfg = *(const short8*)&W2[(size_t)(c32 + nt * 16 + l15) * 128 + ks * 32 + quad * 8];
                acc[nt] = __builtin_amdgcn_mfma_f32_16x16x32_bf16(af, bfg, acc[nt], 0, 0, 0);
            }
        }
        #pragma unroll
        for (int nt = 0; nt < 2; nt++) {
            #pragma unroll
            for (int r = 0; r < 4; r++) {
                int row = r16 + quad * 4 + r;
                s_t[row * STRA + c32 + nt * 16 + l15] = f2bf(ssp(acc[nt][r] + bva[nt]));
            }
        }

        __syncthreads();   // t complete (cross-wave cols needed by GEMM3)

        // ---- GEMM3: h += t @ lin + b ----
        #pragma unroll
        for (int nt = 0; nt < 2; nt++) acc[nt] = (floatx4){0.f, 0.f, 0.f, 0.f};
        #pragma unroll
        for (int ks = 0; ks < 4; ks++) {
            short8 af = *(const short8*)&s_t[(r16 + l15) * STRA + ks * 32 + quad * 8];
            #pragma unroll
            for (int nt = 0; nt < 2; nt++) {
                short8 bfg = *(const short8*)&W3[(size_t)(c32 + nt * 16 + l15) * 128 + ks * 32 + quad * 8];
                acc[nt] = __builtin_amdgcn_mfma_f32_16x16x32_bf16(af, bfg, acc[nt], 0, 0, 0);
            }
        }
        #pragma unroll
        for (int nt = 0; nt < 2; nt++) {
            #pragma unroll
            for (int r = 0; r < 4; r++) {
                int row = r16 + quad * 4 + r;
                s_h[row * STRH + c32 + nt * 16 + l15] += acc[nt][r] + bvb[nt];
            }
        }
        // loop-top __syncthreads covers h
    }

    __syncthreads();

    // ---- head: out = sum_a ssp(h@out1 + b1)@out2 + 32*b2 ----
    const int c16 = (w >> 1) * 16;   // out1 has 64 cols: 4 col tiles x 2 rows
    floatx4 ha = (floatx4){0.f, 0.f, 0.f, 0.f};
    #pragma unroll
    for (int ks = 0; ks < 4; ks++) {
        const float* hp = &s_h[(r16 + l15) * STRH + ks * 32 + quad * 8];
        float4 xa = *(const float4*)hp;
        float4 xb = *(const float4*)(hp + 4);
        unsigned int ap[4];
        ap[0] = pk2bf(xa.x, xa.y); ap[1] = pk2bf(xa.z, xa.w);
        ap[2] = pk2bf(xb.x, xb.y); ap[3] = pk2bf(xb.z, xb.w);
        short8 af;
        __builtin_memcpy(&af, ap, 16);
        short8 bfg = *(const short8*)&WtO[(size_t)(c16 + l15) * 128 + ks * 32 + quad * 8];
        ha = __builtin_amdgcn_mfma_f32_16x16x32_bf16(af, bfg, ha, 0, 0, 0);
    }
    float part = 0.0f;
    {
        float b1o = out1_b[c16 + l15];
        float o2  = out2_w[c16 + l15];
        #pragma unroll
        for (int r = 0; r < 4; r++)
            part += ssp(ha[r] + b1o) * o2;
    }
    #pragma unroll
    for (int off = 32; off > 0; off >>= 1) part += __shfl_down(part, off);
    if (lane == 0) atomicAdd(&s_red, part);
    __syncthreads();
    if (tid == 0) out[blockIdx.x] = s_red + 32.0f * out2_b[0];
}

extern "C" void kernel_launch(void* const* d_in, const int* in_sizes, int n_in,
                              void* d_out, int out_size, void* d_ws, size_t ws_size,
                              hipStream_t stream)
{
    const int*   z      = (const int*)d_in[0];
    const float* pos    = (const float*)d_in[1];
    const int*   eidx   = (const int*)d_in[3];
    const float* emb    = (const float*)d_in[4];
    const float* mlp_w1 = (const float*)d_in[5];
    const float* mlp_b1 = (const float*)d_in[6];
    const float* mlp_w2 = (const float*)d_in[7];
    const float* mlp_b2 = (const float*)d_in[8];
    const float* cf1_w  = (const float*)d_in[9];
    const float* cf2_w  = (const float*)d_in[10];
    const float* cf2_b  = (const float*)d_in[11];
    const float* lin_w  = (const float*)d_in[12];
    const float* lin_b  = (const float*)d_in[13];
    const float* out1_w = (const float*)d_in[14];
    const float* out1_b = (const float*)d_in[15];
    const float* out2_w = (const float*)d_in[16];
    const float* out2_b = (const float*)d_in[17];
    const int E = in_sizes[3] / 2;

    // workspace carve-up (16B-aligned sections)
    char* p = (char*)d_ws;
    uint2* meta = (uint2*)p;                      p += ((size_t)E * 8 + 63) & ~63ULL;
    unsigned int* Tp = (unsigned int*)p;          p += (size_t)3 * KTAB * 128 * 4;
    int* rowptr = (int*)p;                        p += ((size_t)(NATOMS + 1) * 4 + 63) & ~63ULL;
    unsigned short* Ttab = (unsigned short*)p;    p += (size_t)3 * KTAB * 128 * 2;
    unsigned short* Wtall = (unsigned short*)p;   // 9*16384 + 64*128 ushorts

    const int setup_work = E + (NATOMS + 1) + 9 * 16384 + 64 * 128;
    setup_kernel<<<(setup_work + 255) / 256, 256, 0, stream>>>(
        pos, eidx, E, rowptr, cf1_w, cf2_w, lin_w, out1_w, Wtall, meta);
    build_table_kernel<<<dim3(KTAB / 64, 3), 256, 0, stream>>>(
        mlp_w1, mlp_b1, mlp_w2, mlp_b2, Ttab);
    pack_table_kernel<<<3 * KTAB * 128 / 256, 256, 0, stream>>>(Ttab, Tp);

    fused_schnet_kernel<<<NMOL, 512, 0, stream>>>(
        z, emb, rowptr, meta, Tp, Wtall,
        cf2_b, lin_b, out1_b, out2_w, out2_b, (float*)d_out);
}